// Round 5
// baseline (273.420 us; speedup 1.0000x reference)
//
#include <hip/hip_runtime.h>

// GCNBlock: out0 = relu( (D^-1/2 (A+I) D^-1/2) (x W) + b ) + x   [N,128] f32
//           out1 = edge_index echoed (as float values) appended in d_out
// Identity: Agg(xW) = Agg(x) W.
// Round 5: zero-global-atomic CSR build via 2-level bucket counting sort:
//   A1: per-block LDS histogram over dst>>9 buckets (+ fused echo)
//   scanH: column prefix of H + bucket bases
//   A2: scatter packed (dstLow9,src) records to bucket-contiguous brec
//   B: per-bucket 512-bin LDS count/scan -> recs + rowstart + invs
// Then: xs = bf16(invs*x) staging, gather-sum aggregation, MFMA GEMM epilogue.

#define DD 128
#define EPB 8192      // edges per A-block (32 iters x 256 threads)
#define BSH 9         // bucket shift: 512 nodes per bucket
typedef __attribute__((ext_vector_type(8))) short bf16x8;
typedef __attribute__((ext_vector_type(4))) float f32x4;

__device__ __forceinline__ ushort f2bf(float f) {
    unsigned u = __float_as_uint(f);
    unsigned r = (u + 0x7fffu + ((u >> 16) & 1u)) >> 16;  // RNE
    return (ushort)r;
}
__device__ __forceinline__ float bflo(unsigned u) { return __uint_as_float(u << 16); }
__device__ __forceinline__ float bfhi(unsigned u) { return __uint_as_float(u & 0xffff0000u); }

// ---------- dtype sniff: int64 edge data has all-zero high words ----------
__global__ void k_sniff(const int* __restrict__ p, int n_check, int* __restrict__ flag) {
    __shared__ int any_nonzero;
    if (threadIdx.x == 0) any_nonzero = 0;
    __syncthreads();
    int j = threadIdx.x;
    if (j < n_check && p[2 * j + 1] != 0) any_nonzero = 1;
    __syncthreads();
    if (threadIdx.x == 0) *flag = any_nonzero ? 0 : 1;  // 1 => int64 layout
}

__device__ __forceinline__ int ld_src(const int* p, int e, int E, int is64) {
    return is64 ? p[2 * e] : p[e];
}
__device__ __forceinline__ int ld_dst(const int* p, int e, int E, int is64) {
    return is64 ? p[2 * (E + e)] : p[E + e];
}

// ---------- A1: bucket histogram + fused echo (no global atomics) ----------
__global__ __launch_bounds__(256) void kA1(const int* __restrict__ ei, int E, int NB,
                                           float* __restrict__ outTail, int* __restrict__ H,
                                           const int* __restrict__ flagp) {
    __shared__ int hist[256];
    int is64 = *flagp;
    int t = threadIdx.x, a = blockIdx.x;
    if (t < NB) hist[t] = 0;
    __syncthreads();
    int base = a * EPB;
    #pragma unroll 4
    for (int it = 0; it < EPB / 256; ++it) {
        int e = base + it * 256 + t;
        if (e < E) {
            int s = ld_src(ei, e, E, is64);
            int d = ld_dst(ei, e, E, is64);
            outTail[e] = (float)s;
            outTail[E + e] = (float)d;
            atomicAdd(&hist[d >> BSH], 1);
        }
    }
    __syncthreads();
    if (t < NB) H[a * NB + t] = hist[t];
}

// ---------- scanH: H[a][b] -> bucketstart[b] + sum_{a'<a} H[a'][b] ----------
__global__ void k_scanH(int* __restrict__ H, int nA, int NB, int E,
                        int* __restrict__ bucketstart) {
    __shared__ int tot[257];
    int b = threadIdx.x;
    if (b < NB) {
        int acc = 0;
        for (int a = 0; a < nA; ++a) { int v = H[a * NB + b]; H[a * NB + b] = acc; acc += v; }
        tot[b] = acc;
    }
    __syncthreads();
    if (threadIdx.x == 0) {
        int acc = 0;
        for (int bb = 0; bb < NB; ++bb) { int v = tot[bb]; tot[bb] = acc; acc += v; }
        tot[NB] = acc;  // == E
    }
    __syncthreads();
    if (b <= NB) bucketstart[b] = tot[b];
    if (b < NB) {
        int bs = tot[b];
        for (int a = 0; a < nA; ++a) H[a * NB + b] += bs;
    }
}

// ---------- A2: scatter packed records to bucket-contiguous brec ----------
// record = src | (dst&511)<<17   (needs N <= 131072)
__global__ __launch_bounds__(256) void kA2(const int* __restrict__ ei, int E, int NB,
                                           const int* __restrict__ H, unsigned* __restrict__ brec,
                                           const int* __restrict__ flagp) {
    __shared__ int cur[256];
    int is64 = *flagp;
    int t = threadIdx.x, a = blockIdx.x;
    if (t < NB) cur[t] = H[a * NB + t];
    __syncthreads();
    int base = a * EPB;
    #pragma unroll 4
    for (int it = 0; it < EPB / 256; ++it) {
        int e = base + it * 256 + t;
        if (e < E) {
            int s = ld_src(ei, e, E, is64);
            int d = ld_dst(ei, e, E, is64);
            int pos = atomicAdd(&cur[d >> BSH], 1);  // LDS atomic
            brec[pos] = (unsigned)s | ((unsigned)(d & 511) << 17);
        }
    }
}

// ---------- B: per-bucket CSR finalize: recs + rowstart + invs ----------
__global__ __launch_bounds__(256) void kB(const unsigned* __restrict__ brec,
                                          const int* __restrict__ bucketstart, int NB, int N,
                                          int E, unsigned* __restrict__ recs,
                                          int* __restrict__ rowstart, float* __restrict__ invs) {
    __shared__ int hist[512];
    __shared__ int scan[513];
    __shared__ int cur[512];
    int b = blockIdx.x, t = threadIdx.x;
    int lo = bucketstart[b], hi = bucketstart[b + 1];
    hist[t] = 0; hist[t + 256] = 0;
    __syncthreads();
    for (int i = lo + t; i < hi; i += 256) atomicAdd(&hist[brec[i] >> 17], 1);
    __syncthreads();
    if (t == 0) {
        int acc = 0;
        for (int j = 0; j < 512; ++j) { scan[j] = acc; acc += hist[j]; }
        scan[512] = acc;
    }
    __syncthreads();
    int nodeBase = b << BSH;
    #pragma unroll
    for (int j = t; j < 512; j += 256) {
        int node = nodeBase + j;
        if (node < N) {
            rowstart[node] = lo + scan[j];
            invs[node] = rsqrtf((float)(1 + hist[j]));  // deg includes self-loop
        }
        cur[j] = lo + scan[j];
    }
    if (b == NB - 1 && t == 0) rowstart[N] = E;
    __syncthreads();
    for (int i = lo + t; i < hi; i += 256) {
        unsigned r = brec[i];
        int pos = atomicAdd(&cur[r >> 17], 1);  // LDS atomic
        recs[pos] = r & 0x1FFFFu;
    }
}

// ---------- convert x -> bf16 pre-scaled by invs: xs[i] = bf16(invs[node]*x[i]) ----------
__global__ void k_cvt_xs(const float2* __restrict__ x2, const float* __restrict__ invs,
                         unsigned* __restrict__ xs, int n2) {
    int i = blockIdx.x * blockDim.x + threadIdx.x;
    if (i < n2) {
        float w = invs[i >> 6];
        float2 v = x2[i];
        xs[i] = (unsigned)f2bf(w * v.x) | ((unsigned)f2bf(w * v.y) << 16);
    }
}

// ---------- convert W -> bf16 transposed: Wt[c][k] = bf16(W[k][c]) ----------
__global__ void k_cvt_W(const float* __restrict__ W, ushort* __restrict__ Wt) {
    int i = blockIdx.x * blockDim.x + threadIdx.x;
    if (i < DD * DD) {
        int c = i >> 7, k = i & 127;
        Wt[i] = f2bf(W[k * DD + c]);
    }
}

// ---------- aggregation: 1 wave/node; sum pre-scaled bf16 rows, scale by invs[node] ----------
__global__ void k_agg_s(const unsigned* __restrict__ xs, const int* __restrict__ rowstart,
                        const float* __restrict__ invs, const unsigned* __restrict__ recs,
                        int N, unsigned* __restrict__ aggh) {
    int node = blockIdx.x * 4 + (threadIdx.x >> 6);
    int lane = threadIdx.x & 63;
    if (node >= N) return;
    float wn = invs[node];
    unsigned us = xs[(size_t)node * 64 + lane];  // self: xs[node]*wn = invs^2 * x
    float accx = bflo(us), accy = bfhi(us);
    int e = rowstart[node], e1 = rowstart[node + 1];
    for (; e + 8 <= e1; e += 8) {
        unsigned s0 = recs[e + 0], s1 = recs[e + 1], s2 = recs[e + 2], s3 = recs[e + 3];
        unsigned s4 = recs[e + 4], s5 = recs[e + 5], s6 = recs[e + 6], s7 = recs[e + 7];
        unsigned v0 = xs[(size_t)s0 * 64 + lane];
        unsigned v1 = xs[(size_t)s1 * 64 + lane];
        unsigned v2 = xs[(size_t)s2 * 64 + lane];
        unsigned v3 = xs[(size_t)s3 * 64 + lane];
        unsigned v4 = xs[(size_t)s4 * 64 + lane];
        unsigned v5 = xs[(size_t)s5 * 64 + lane];
        unsigned v6 = xs[(size_t)s6 * 64 + lane];
        unsigned v7 = xs[(size_t)s7 * 64 + lane];
        accx += bflo(v0); accy += bfhi(v0);
        accx += bflo(v1); accy += bfhi(v1);
        accx += bflo(v2); accy += bfhi(v2);
        accx += bflo(v3); accy += bfhi(v3);
        accx += bflo(v4); accy += bfhi(v4);
        accx += bflo(v5); accy += bfhi(v5);
        accx += bflo(v6); accy += bfhi(v6);
        accx += bflo(v7); accy += bfhi(v7);
    }
    for (; e < e1; ++e) {
        unsigned v0 = xs[(size_t)recs[e] * 64 + lane];
        accx += bflo(v0); accy += bfhi(v0);
    }
    float ox = accx * wn, oy = accy * wn;
    aggh[(size_t)node * 64 + lane] = (unsigned)f2bf(ox) | ((unsigned)f2bf(oy) << 16);
}

// ---------- MFMA GEMM + bias + relu + residual ----------
// A frag: row=lane&15, k=(lane>>4)*8+j (contig, aggh row-major)
// B frag: col=lane&15, k=(lane>>4)*8+j (contig, Wt[c][k])
// C/D:    col=lane&15, row=(lane>>4)*4+reg   [m89-verified]
__global__ __launch_bounds__(256) void k_gemm_mfma(const ushort* __restrict__ aggh,
                                                   const ushort* __restrict__ Wt,
                                                   const float* __restrict__ bb,
                                                   const float* __restrict__ x,
                                                   float* __restrict__ out, int N) {
    int wave = threadIdx.x >> 6, lane = threadIdx.x & 63;
    int rowBase = blockIdx.x * 64 + wave * 16;
    int rfrag = lane & 15, kgrp = lane >> 4;
    f32x4 zero = {0.f, 0.f, 0.f, 0.f};
    f32x4 acc[8];
    #pragma unroll
    for (int n = 0; n < 8; ++n) acc[n] = zero;

    int arow = rowBase + rfrag;
    bool av = arow < N;
    const ushort* abase = aggh + (size_t)(av ? arow : 0) * DD + kgrp * 8;
    const ushort* bbase = Wt + rfrag * DD + kgrp * 8;

    #pragma unroll
    for (int ks = 0; ks < 4; ++ks) {
        bf16x8 a = {0, 0, 0, 0, 0, 0, 0, 0};
        if (av) a = *(const bf16x8*)(abase + ks * 32);
        #pragma unroll
        for (int n = 0; n < 8; ++n) {
            bf16x8 bf = *(const bf16x8*)(bbase + n * 16 * DD + ks * 32);
            acc[n] = __builtin_amdgcn_mfma_f32_16x16x32_bf16(a, bf, acc[n], 0, 0, 0);
        }
    }

    int colb = lane & 15, rq = lane >> 4;
    #pragma unroll
    for (int n = 0; n < 8; ++n) {
        int col = n * 16 + colb;
        float bias = bb[col];
        #pragma unroll
        for (int j = 0; j < 4; ++j) {
            int row = rowBase + rq * 4 + j;
            if (row < N) {
                size_t o = (size_t)row * DD + col;
                out[o] = fmaxf(acc[n][j] + bias, 0.f) + x[o];
            }
        }
    }
}

// =================== fallback path (shape/ws outside new-path limits) ===================
__global__ void k_count_echo(const int* __restrict__ ei, int E, int* __restrict__ cnt,
                             float* __restrict__ outTail, unsigned* __restrict__ rank,
                             const int* __restrict__ flagp) {
    int is64 = *flagp;
    int e = blockIdx.x * blockDim.x + threadIdx.x;
    if (e < E) {
        int s = ld_src(ei, e, E, is64);
        int d = ld_dst(ei, e, E, is64);
        outTail[e] = (float)s;
        outTail[E + e] = (float)d;
        rank[e] = (unsigned)atomicAdd(&cnt[d], 1);
    }
}

__global__ void k_scan1(const int* __restrict__ cnt, int N, int* __restrict__ rowstart,
                        int* __restrict__ bsum) {
    __shared__ int s[1024];
    int tid = threadIdx.x;
    int i = blockIdx.x * 1024 + tid;
    int v = (i < N) ? cnt[i] : 0;
    s[tid] = v;
    __syncthreads();
    for (int off = 1; off < 1024; off <<= 1) {
        int t2 = (tid >= off) ? s[tid - off] : 0;
        __syncthreads();
        s[tid] += t2;
        __syncthreads();
    }
    if (i < N) rowstart[i] = s[tid] - v;
    if (tid == 1023) bsum[blockIdx.x] = s[1023];
}

__global__ void k_scan2(const int* __restrict__ bsum, int nblk, int* __restrict__ boff) {
    __shared__ int s[128];
    int t = threadIdx.x;
    if (t < nblk) s[t] = bsum[t];
    __syncthreads();
    if (t == 0) {
        int a = 0;
        for (int i = 0; i < nblk; i++) { int v = s[i]; s[i] = a; a += v; }
    }
    __syncthreads();
    if (t < nblk) boff[t] = s[t];
}

__global__ void k_scan3(int N, int E, int* __restrict__ rowstart, const int* __restrict__ boff,
                        const int* __restrict__ cnt, float* __restrict__ invs) {
    int i = blockIdx.x * blockDim.x + threadIdx.x;
    if (i < N) {
        int r = rowstart[i] + boff[i >> 10];
        rowstart[i] = r;
        invs[i] = rsqrtf((float)(1 + cnt[i]));
    }
    if (i == 0 && blockIdx.x == 0) rowstart[N] = E;
}

__global__ void k_fill_r(const int* __restrict__ ei, int E, const int* __restrict__ rowstart,
                         const unsigned* __restrict__ rank, unsigned* __restrict__ recs,
                         const int* __restrict__ flagp) {
    int is64 = *flagp;
    int e = blockIdx.x * blockDim.x + threadIdx.x;
    if (e < E) {
        int d = ld_dst(ei, e, E, is64);
        int s = ld_src(ei, e, E, is64);
        recs[rowstart[d] + rank[e]] = (unsigned)s;
    }
}

__global__ void k_agg_f32(const float* __restrict__ x, const int* __restrict__ rowstart,
                          const float* __restrict__ invs, const unsigned* __restrict__ recs,
                          int N, float* __restrict__ aggOut) {
    int node = blockIdx.x * 4 + (threadIdx.x >> 6);
    int lane = threadIdx.x & 63;
    if (node >= N) return;
    const float2* xr = (const float2*)x;
    float wn = invs[node];
    float2 xself = xr[(size_t)node * 64 + lane];
    float accx = wn * xself.x, accy = wn * xself.y;
    int e = rowstart[node], e1 = rowstart[node + 1];
    for (; e < e1; ++e) {
        unsigned s = recs[e];
        float w = invs[s];
        float2 v = xr[(size_t)s * 64 + lane];
        accx = fmaf(w, v.x, accx); accy = fmaf(w, v.y, accy);
    }
    float2 o; o.x = accx * wn; o.y = accy * wn;
    ((float2*)aggOut)[(size_t)node * 64 + lane] = o;
}

#define GROWS 32
__global__ __launch_bounds__(128) void k_gemm_f32(float* __restrict__ out, const float* __restrict__ Wm,
                                                  const float* __restrict__ bb,
                                                  const float* __restrict__ x, int N) {
    __shared__ float Ws[64 * DD];
    __shared__ float As[DD * GROWS];
    int t = threadIdx.x;
    int rowBase = blockIdx.x * GROWS;
    {
        int r = t & 31, kq = t >> 5;
        if (rowBase + r < N) {
            const float4* Av = (const float4*)(out + (size_t)(rowBase + r) * DD);
            #pragma unroll
            for (int q = 0; q < 8; q++) {
                float4 v = Av[kq * 8 + q];
                int k = (kq * 8 + q) * 4;
                As[(k + 0) * GROWS + r] = v.x;
                As[(k + 1) * GROWS + r] = v.y;
                As[(k + 2) * GROWS + r] = v.z;
                As[(k + 3) * GROWS + r] = v.w;
            }
        } else {
            #pragma unroll
            for (int q = 0; q < 8; q++) {
                int k = (kq * 8 + q) * 4;
                As[(k + 0) * GROWS + r] = 0.f;
                As[(k + 1) * GROWS + r] = 0.f;
                As[(k + 2) * GROWS + r] = 0.f;
                As[(k + 3) * GROWS + r] = 0.f;
            }
        }
    }
    int tx = t & 15, ty = t >> 4;
    int c0 = tx * 8, r0 = ty * 4;
    float acc[4][8];
    #pragma unroll
    for (int i = 0; i < 4; i++)
        #pragma unroll
        for (int j = 0; j < 8; j++) acc[i][j] = 0.f;
    for (int kk = 0; kk < DD; kk += 64) {
        __syncthreads();
        const float4* Wv = (const float4*)(Wm + (size_t)kk * DD);
        #pragma unroll
        for (int i = 0; i < 16; i++) ((float4*)Ws)[t + i * 128] = Wv[t + i * 128];
        __syncthreads();
        #pragma unroll 4
        for (int k = 0; k < 64; k++) {
            const float4 a = *(const float4*)&As[(kk + k) * GROWS + r0];
            const float4 w0 = *(const float4*)&Ws[k * DD + c0];
            const float4 w1 = *(const float4*)&Ws[k * DD + c0 + 4];
            const float av[4] = {a.x, a.y, a.z, a.w};
            const float wv[8] = {w0.x, w0.y, w0.z, w0.w, w1.x, w1.y, w1.z, w1.w};
            #pragma unroll
            for (int i = 0; i < 4; i++)
                #pragma unroll
                for (int j = 0; j < 8; j++) acc[i][j] = fmaf(av[i], wv[j], acc[i][j]);
        }
    }
    float bv[8];
    {
        float4 b0 = *(const float4*)&bb[c0];
        float4 b1 = *(const float4*)&bb[c0 + 4];
        bv[0] = b0.x; bv[1] = b0.y; bv[2] = b0.z; bv[3] = b0.w;
        bv[4] = b1.x; bv[5] = b1.y; bv[6] = b1.z; bv[7] = b1.w;
    }
    #pragma unroll
    for (int i = 0; i < 4; i++) {
        int row = rowBase + r0 + i;
        if (row < N) {
            const float4 xv0 = *(const float4*)&x[(size_t)row * DD + c0];
            const float4 xv1 = *(const float4*)&x[(size_t)row * DD + c0 + 4];
            float4 o0, o1;
            o0.x = fmaxf(acc[i][0] + bv[0], 0.f) + xv0.x;
            o0.y = fmaxf(acc[i][1] + bv[1], 0.f) + xv0.y;
            o0.z = fmaxf(acc[i][2] + bv[2], 0.f) + xv0.z;
            o0.w = fmaxf(acc[i][3] + bv[3], 0.f) + xv0.w;
            o1.x = fmaxf(acc[i][4] + bv[4], 0.f) + xv1.x;
            o1.y = fmaxf(acc[i][5] + bv[5], 0.f) + xv1.y;
            o1.z = fmaxf(acc[i][6] + bv[6], 0.f) + xv1.z;
            o1.w = fmaxf(acc[i][7] + bv[7], 0.f) + xv1.w;
            *(float4*)&out[(size_t)row * DD + c0] = o0;
            *(float4*)&out[(size_t)row * DD + c0 + 4] = o1;
        }
    }
}

extern "C" void kernel_launch(void* const* d_in, const int* in_sizes, int n_in,
                              void* d_out, int out_size, void* d_ws, size_t ws_size,
                              hipStream_t stream) {
    const float* x = (const float*)d_in[0];
    const float* W = (const float*)d_in[1];
    const float* b = (const float*)d_in[2];
    const int*   ei = (const int*)d_in[3];
    int N = in_sizes[0] / DD;
    int E = in_sizes[3] / 2;
    float* out = (float*)d_out;
    float* outTail = out + (size_t)N * DD;

    int NB = (N + 511) >> BSH;          // buckets of 512 nodes
    int nA = (E + EPB - 1) / EPB;       // A-pass blocks

    // new-path workspace layout
    char* wsb = (char*)d_ws;
    size_t off = 0;
    unsigned* brec = (unsigned*)(wsb + off);  off += (size_t)E * 4;
    unsigned* recs = (unsigned*)(wsb + off);  off += (size_t)E * 4;
    unsigned* xs   = (unsigned*)(wsb + off);  off += (size_t)N * 64 * 4;
    unsigned* aggh = (unsigned*)(wsb + off);  off += (size_t)N * 64 * 4;
    ushort*   Wt   = (ushort*)(wsb + off);    off += (size_t)DD * DD * 2;
    int* H         = (int*)(wsb + off);       off += (size_t)nA * NB * 4;
    int* bucketstart = (int*)(wsb + off);     off += (size_t)(NB + 1) * 4;
    int* rowstart  = (int*)(wsb + off);       off += (size_t)(N + 1) * 4;
    float* invs    = (float*)(wsb + off);     off += (size_t)N * 4;
    int* flag      = (int*)(wsb + off);       off += 64;

    bool newpath = (ws_size >= off) && (NB <= 256) && (N <= 131072);

    if (newpath) {
        k_sniff<<<1, 1024, 0, stream>>>(ei, 1024, flag);
        kA1<<<nA, 256, 0, stream>>>(ei, E, NB, outTail, H, flag);
        k_scanH<<<1, 256, 0, stream>>>(H, nA, NB, E, bucketstart);
        kA2<<<nA, 256, 0, stream>>>(ei, E, NB, H, brec, flag);
        kB<<<NB, 256, 0, stream>>>(brec, bucketstart, NB, N, E, recs, rowstart, invs);
        int n2 = N * 64;
        k_cvt_xs<<<(n2 + 255) / 256, 256, 0, stream>>>((const float2*)x, invs, xs, n2);
        k_cvt_W<<<(DD * DD + 255) / 256, 256, 0, stream>>>(W, Wt);
        k_agg_s<<<(N + 3) / 4, 256, 0, stream>>>(xs, rowstart, invs, recs, N, aggh);
        k_gemm_mfma<<<(N + 63) / 64, 256, 0, stream>>>((const ushort*)aggh, Wt, b, x, out, N);
    } else {
        // fallback: round-4 rank-based build + f32 compute (known good)
        off = 0;
        unsigned* recsF = (unsigned*)(wsb + off);  off += (size_t)E * 4;
        unsigned* rank  = (unsigned*)(wsb + off);  off += (size_t)E * 4;
        int* cnt        = (int*)(wsb + off);       off += (size_t)N * 4;
        int* rowstartF  = (int*)(wsb + off);       off += (size_t)(N + 1) * 4;
        float* invsF    = (float*)(wsb + off);     off += (size_t)N * 4;
        int* bsum       = (int*)(wsb + off);       off += 512 * 4;
        int* boff       = (int*)(wsb + off);       off += 512 * 4;
        int* flagF      = (int*)(wsb + off);

        hipMemsetAsync(cnt, 0, sizeof(int) * (size_t)N, stream);
        k_sniff<<<1, 1024, 0, stream>>>(ei, 1024, flagF);
        k_count_echo<<<(E + 255) / 256, 256, 0, stream>>>(ei, E, cnt, outTail, rank, flagF);
        int nblk = (N + 1023) / 1024;
        k_scan1<<<nblk, 1024, 0, stream>>>(cnt, N, rowstartF, bsum);
        k_scan2<<<1, 128, 0, stream>>>(bsum, nblk, boff);
        k_scan3<<<(N + 255) / 256, 256, 0, stream>>>(N, E, rowstartF, boff, cnt, invsF);
        k_fill_r<<<(E + 255) / 256, 256, 0, stream>>>(ei, E, rowstartF, rank, recsF, flagF);
        k_agg_f32<<<(N + 3) / 4, 256, 0, stream>>>(x, rowstartF, invsF, recsF, N, out);
        k_gemm_f32<<<(N + GROWS - 1) / GROWS, 128, 0, stream>>>(out, W, b, x, N);
    }
}

// Round 6
// 206.131 us; speedup vs baseline: 1.3264x; 1.3264x over previous
//
#include <hip/hip_runtime.h>

// GCNBlock: out0 = relu( (D^-1/2 (A+I) D^-1/2) (x W) + b ) + x   [N,128] f32
//           out1 = edge_index echoed (as float values) appended in d_out
// Identity: Agg(xW) = Agg(x) W.
// Round 6: fix round-5's serial k_scanH (75us, 1 block, serial loops) with
// fully parallel column scans: k_scanH1 (NB blocks) + k_scanH2 (1 block),
// bucket base folded into kA2's cursor init. Everything else unchanged.

#define DD 128
#define EPB 8192      // edges per A-block (32 iters x 256 threads)
#define BSH 9         // bucket shift: 512 nodes per bucket
typedef __attribute__((ext_vector_type(8))) short bf16x8;
typedef __attribute__((ext_vector_type(4))) float f32x4;

__device__ __forceinline__ ushort f2bf(float f) {
    unsigned u = __float_as_uint(f);
    unsigned r = (u + 0x7fffu + ((u >> 16) & 1u)) >> 16;  // RNE
    return (ushort)r;
}
__device__ __forceinline__ float bflo(unsigned u) { return __uint_as_float(u << 16); }
__device__ __forceinline__ float bfhi(unsigned u) { return __uint_as_float(u & 0xffff0000u); }

// ---------- dtype sniff: int64 edge data has all-zero high words ----------
__global__ void k_sniff(const int* __restrict__ p, int n_check, int* __restrict__ flag) {
    __shared__ int any_nonzero;
    if (threadIdx.x == 0) any_nonzero = 0;
    __syncthreads();
    int j = threadIdx.x;
    if (j < n_check && p[2 * j + 1] != 0) any_nonzero = 1;
    __syncthreads();
    if (threadIdx.x == 0) *flag = any_nonzero ? 0 : 1;  // 1 => int64 layout
}

__device__ __forceinline__ int ld_src(const int* p, int e, int E, int is64) {
    return is64 ? p[2 * e] : p[e];
}
__device__ __forceinline__ int ld_dst(const int* p, int e, int E, int is64) {
    return is64 ? p[2 * (E + e)] : p[E + e];
}

// ---------- A1: bucket histogram + fused echo (no global atomics) ----------
__global__ __launch_bounds__(256) void kA1(const int* __restrict__ ei, int E, int NB,
                                           float* __restrict__ outTail, int* __restrict__ H,
                                           const int* __restrict__ flagp) {
    __shared__ int hist[256];
    int is64 = *flagp;
    int t = threadIdx.x, a = blockIdx.x;
    if (t < NB) hist[t] = 0;
    __syncthreads();
    int base = a * EPB;
    #pragma unroll 4
    for (int it = 0; it < EPB / 256; ++it) {
        int e = base + it * 256 + t;
        if (e < E) {
            int s = ld_src(ei, e, E, is64);
            int d = ld_dst(ei, e, E, is64);
            outTail[e] = (float)s;
            outTail[E + e] = (float)d;
            atomicAdd(&hist[d >> BSH], 1);
        }
    }
    __syncthreads();
    if (t < NB) H[a * NB + t] = hist[t];
}

// ---------- scanH1: parallel per-column exclusive scan of H (NB blocks) ----------
__global__ __launch_bounds__(256) void k_scanH1(int* __restrict__ H, int nA, int NB,
                                                int* __restrict__ colsum) {
    __shared__ int s[256];
    int b = blockIdx.x, t = threadIdx.x;
    int v = (t < nA) ? H[t * NB + b] : 0;
    s[t] = v;
    __syncthreads();
    #pragma unroll
    for (int off = 1; off < 256; off <<= 1) {
        int u = (t >= off) ? s[t - off] : 0;
        __syncthreads();
        s[t] += u;
        __syncthreads();
    }
    if (t < nA) H[t * NB + b] = s[t] - v;  // exclusive within column
    if (t == 0) colsum[b] = s[nA - 1];     // column total
}

// ---------- scanH2: exclusive scan of colsum -> bucketstart (1 block) ----------
__global__ __launch_bounds__(256) void k_scanH2(const int* __restrict__ colsum, int NB, int E,
                                                int* __restrict__ bucketstart) {
    __shared__ int s[256];
    int t = threadIdx.x;
    int v = (t < NB) ? colsum[t] : 0;
    s[t] = v;
    __syncthreads();
    #pragma unroll
    for (int off = 1; off < 256; off <<= 1) {
        int u = (t >= off) ? s[t - off] : 0;
        __syncthreads();
        s[t] += u;
        __syncthreads();
    }
    if (t < NB) bucketstart[t] = s[t] - v;
    if (t == 0) bucketstart[NB] = E;
}

// ---------- A2: scatter packed records to bucket-contiguous brec ----------
// record = src | (dst&511)<<17   (needs N <= 131072)
__global__ __launch_bounds__(256) void kA2(const int* __restrict__ ei, int E, int NB,
                                           const int* __restrict__ H,
                                           const int* __restrict__ bucketstart,
                                           unsigned* __restrict__ brec,
                                           const int* __restrict__ flagp) {
    __shared__ int cur[256];
    int is64 = *flagp;
    int t = threadIdx.x, a = blockIdx.x;
    if (t < NB) cur[t] = H[a * NB + t] + bucketstart[t];
    __syncthreads();
    int base = a * EPB;
    #pragma unroll 4
    for (int it = 0; it < EPB / 256; ++it) {
        int e = base + it * 256 + t;
        if (e < E) {
            int s = ld_src(ei, e, E, is64);
            int d = ld_dst(ei, e, E, is64);
            int pos = atomicAdd(&cur[d >> BSH], 1);  // LDS atomic
            brec[pos] = (unsigned)s | ((unsigned)(d & 511) << 17);
        }
    }
}

// ---------- B: per-bucket CSR finalize: recs + rowstart + invs ----------
__global__ __launch_bounds__(256) void kB(const unsigned* __restrict__ brec,
                                          const int* __restrict__ bucketstart, int NB, int N,
                                          int E, unsigned* __restrict__ recs,
                                          int* __restrict__ rowstart, float* __restrict__ invs) {
    __shared__ int hist[512];
    __shared__ int scan[513];
    __shared__ int cur[512];
    int b = blockIdx.x, t = threadIdx.x;
    int lo = bucketstart[b], hi = bucketstart[b + 1];
    hist[t] = 0; hist[t + 256] = 0;
    __syncthreads();
    for (int i = lo + t; i < hi; i += 256) atomicAdd(&hist[brec[i] >> 17], 1);
    __syncthreads();
    if (t == 0) {
        int acc = 0;
        for (int j = 0; j < 512; ++j) { scan[j] = acc; acc += hist[j]; }
        scan[512] = acc;
    }
    __syncthreads();
    int nodeBase = b << BSH;
    #pragma unroll
    for (int j = t; j < 512; j += 256) {
        int node = nodeBase + j;
        if (node < N) {
            rowstart[node] = lo + scan[j];
            invs[node] = rsqrtf((float)(1 + hist[j]));  // deg includes self-loop
        }
        cur[j] = lo + scan[j];
    }
    if (b == NB - 1 && t == 0) rowstart[N] = E;
    __syncthreads();
    for (int i = lo + t; i < hi; i += 256) {
        unsigned r = brec[i];
        int pos = atomicAdd(&cur[r >> 17], 1);  // LDS atomic
        recs[pos] = r & 0x1FFFFu;
    }
}

// ---------- convert x -> bf16 pre-scaled by invs: xs[i] = bf16(invs[node]*x[i]) ----------
__global__ void k_cvt_xs(const float2* __restrict__ x2, const float* __restrict__ invs,
                         unsigned* __restrict__ xs, int n2) {
    int i = blockIdx.x * blockDim.x + threadIdx.x;
    if (i < n2) {
        float w = invs[i >> 6];
        float2 v = x2[i];
        xs[i] = (unsigned)f2bf(w * v.x) | ((unsigned)f2bf(w * v.y) << 16);
    }
}

// ---------- convert W -> bf16 transposed: Wt[c][k] = bf16(W[k][c]) ----------
__global__ void k_cvt_W(const float* __restrict__ W, ushort* __restrict__ Wt) {
    int i = blockIdx.x * blockDim.x + threadIdx.x;
    if (i < DD * DD) {
        int c = i >> 7, k = i & 127;
        Wt[i] = f2bf(W[k * DD + c]);
    }
}

// ---------- aggregation: 1 wave/node; sum pre-scaled bf16 rows, scale by invs[node] ----------
__global__ void k_agg_s(const unsigned* __restrict__ xs, const int* __restrict__ rowstart,
                        const float* __restrict__ invs, const unsigned* __restrict__ recs,
                        int N, unsigned* __restrict__ aggh) {
    int node = blockIdx.x * 4 + (threadIdx.x >> 6);
    int lane = threadIdx.x & 63;
    if (node >= N) return;
    float wn = invs[node];
    unsigned us = xs[(size_t)node * 64 + lane];  // self: xs[node]*wn = invs^2 * x
    float accx = bflo(us), accy = bfhi(us);
    int e = rowstart[node], e1 = rowstart[node + 1];
    for (; e + 8 <= e1; e += 8) {
        unsigned s0 = recs[e + 0], s1 = recs[e + 1], s2 = recs[e + 2], s3 = recs[e + 3];
        unsigned s4 = recs[e + 4], s5 = recs[e + 5], s6 = recs[e + 6], s7 = recs[e + 7];
        unsigned v0 = xs[(size_t)s0 * 64 + lane];
        unsigned v1 = xs[(size_t)s1 * 64 + lane];
        unsigned v2 = xs[(size_t)s2 * 64 + lane];
        unsigned v3 = xs[(size_t)s3 * 64 + lane];
        unsigned v4 = xs[(size_t)s4 * 64 + lane];
        unsigned v5 = xs[(size_t)s5 * 64 + lane];
        unsigned v6 = xs[(size_t)s6 * 64 + lane];
        unsigned v7 = xs[(size_t)s7 * 64 + lane];
        accx += bflo(v0); accy += bfhi(v0);
        accx += bflo(v1); accy += bfhi(v1);
        accx += bflo(v2); accy += bfhi(v2);
        accx += bflo(v3); accy += bfhi(v3);
        accx += bflo(v4); accy += bfhi(v4);
        accx += bflo(v5); accy += bfhi(v5);
        accx += bflo(v6); accy += bfhi(v6);
        accx += bflo(v7); accy += bfhi(v7);
    }
    for (; e < e1; ++e) {
        unsigned v0 = xs[(size_t)recs[e] * 64 + lane];
        accx += bflo(v0); accy += bfhi(v0);
    }
    float ox = accx * wn, oy = accy * wn;
    aggh[(size_t)node * 64 + lane] = (unsigned)f2bf(ox) | ((unsigned)f2bf(oy) << 16);
}

// ---------- MFMA GEMM + bias + relu + residual ----------
// A frag: row=lane&15, k=(lane>>4)*8+j (contig, aggh row-major)
// B frag: col=lane&15, k=(lane>>4)*8+j (contig, Wt[c][k])
// C/D:    col=lane&15, row=(lane>>4)*4+reg   [m89-verified]
__global__ __launch_bounds__(256) void k_gemm_mfma(const ushort* __restrict__ aggh,
                                                   const ushort* __restrict__ Wt,
                                                   const float* __restrict__ bb,
                                                   const float* __restrict__ x,
                                                   float* __restrict__ out, int N) {
    int wave = threadIdx.x >> 6, lane = threadIdx.x & 63;
    int rowBase = blockIdx.x * 64 + wave * 16;
    int rfrag = lane & 15, kgrp = lane >> 4;
    f32x4 zero = {0.f, 0.f, 0.f, 0.f};
    f32x4 acc[8];
    #pragma unroll
    for (int n = 0; n < 8; ++n) acc[n] = zero;

    int arow = rowBase + rfrag;
    bool av = arow < N;
    const ushort* abase = aggh + (size_t)(av ? arow : 0) * DD + kgrp * 8;
    const ushort* bbase = Wt + rfrag * DD + kgrp * 8;

    #pragma unroll
    for (int ks = 0; ks < 4; ++ks) {
        bf16x8 a = {0, 0, 0, 0, 0, 0, 0, 0};
        if (av) a = *(const bf16x8*)(abase + ks * 32);
        #pragma unroll
        for (int n = 0; n < 8; ++n) {
            bf16x8 bf = *(const bf16x8*)(bbase + n * 16 * DD + ks * 32);
            acc[n] = __builtin_amdgcn_mfma_f32_16x16x32_bf16(a, bf, acc[n], 0, 0, 0);
        }
    }

    int colb = lane & 15, rq = lane >> 4;
    #pragma unroll
    for (int n = 0; n < 8; ++n) {
        int col = n * 16 + colb;
        float bias = bb[col];
        #pragma unroll
        for (int j = 0; j < 4; ++j) {
            int row = rowBase + rq * 4 + j;
            if (row < N) {
                size_t o = (size_t)row * DD + col;
                out[o] = fmaxf(acc[n][j] + bias, 0.f) + x[o];
            }
        }
    }
}

// =================== fallback path (shape/ws outside new-path limits) ===================
__global__ void k_count_echo(const int* __restrict__ ei, int E, int* __restrict__ cnt,
                             float* __restrict__ outTail, unsigned* __restrict__ rank,
                             const int* __restrict__ flagp) {
    int is64 = *flagp;
    int e = blockIdx.x * blockDim.x + threadIdx.x;
    if (e < E) {
        int s = ld_src(ei, e, E, is64);
        int d = ld_dst(ei, e, E, is64);
        outTail[e] = (float)s;
        outTail[E + e] = (float)d;
        rank[e] = (unsigned)atomicAdd(&cnt[d], 1);
    }
}

__global__ void k_scan1(const int* __restrict__ cnt, int N, int* __restrict__ rowstart,
                        int* __restrict__ bsum) {
    __shared__ int s[1024];
    int tid = threadIdx.x;
    int i = blockIdx.x * 1024 + tid;
    int v = (i < N) ? cnt[i] : 0;
    s[tid] = v;
    __syncthreads();
    for (int off = 1; off < 1024; off <<= 1) {
        int t2 = (tid >= off) ? s[tid - off] : 0;
        __syncthreads();
        s[tid] += t2;
        __syncthreads();
    }
    if (i < N) rowstart[i] = s[tid] - v;
    if (tid == 1023) bsum[blockIdx.x] = s[1023];
}

__global__ void k_scan2(const int* __restrict__ bsum, int nblk, int* __restrict__ boff) {
    __shared__ int s[128];
    int t = threadIdx.x;
    if (t < nblk) s[t] = bsum[t];
    __syncthreads();
    if (t == 0) {
        int a = 0;
        for (int i = 0; i < nblk; i++) { int v = s[i]; s[i] = a; a += v; }
    }
    __syncthreads();
    if (t < nblk) boff[t] = s[t];
}

__global__ void k_scan3(int N, int E, int* __restrict__ rowstart, const int* __restrict__ boff,
                        const int* __restrict__ cnt, float* __restrict__ invs) {
    int i = blockIdx.x * blockDim.x + threadIdx.x;
    if (i < N) {
        int r = rowstart[i] + boff[i >> 10];
        rowstart[i] = r;
        invs[i] = rsqrtf((float)(1 + cnt[i]));
    }
    if (i == 0 && blockIdx.x == 0) rowstart[N] = E;
}

__global__ void k_fill_r(const int* __restrict__ ei, int E, const int* __restrict__ rowstart,
                         const unsigned* __restrict__ rank, unsigned* __restrict__ recs,
                         const int* __restrict__ flagp) {
    int is64 = *flagp;
    int e = blockIdx.x * blockDim.x + threadIdx.x;
    if (e < E) {
        int d = ld_dst(ei, e, E, is64);
        int s = ld_src(ei, e, E, is64);
        recs[rowstart[d] + rank[e]] = (unsigned)s;
    }
}

__global__ void k_agg_f32(const float* __restrict__ x, const int* __restrict__ rowstart,
                          const float* __restrict__ invs, const unsigned* __restrict__ recs,
                          int N, float* __restrict__ aggOut) {
    int node = blockIdx.x * 4 + (threadIdx.x >> 6);
    int lane = threadIdx.x & 63;
    if (node >= N) return;
    const float2* xr = (const float2*)x;
    float wn = invs[node];
    float2 xself = xr[(size_t)node * 64 + lane];
    float accx = wn * xself.x, accy = wn * xself.y;
    int e = rowstart[node], e1 = rowstart[node + 1];
    for (; e < e1; ++e) {
        unsigned s = recs[e];
        float w = invs[s];
        float2 v = xr[(size_t)s * 64 + lane];
        accx = fmaf(w, v.x, accx); accy = fmaf(w, v.y, accy);
    }
    float2 o; o.x = accx * wn; o.y = accy * wn;
    ((float2*)aggOut)[(size_t)node * 64 + lane] = o;
}

#define GROWS 32
__global__ __launch_bounds__(128) void k_gemm_f32(float* __restrict__ out, const float* __restrict__ Wm,
                                                  const float* __restrict__ bb,
                                                  const float* __restrict__ x, int N) {
    __shared__ float Ws[64 * DD];
    __shared__ float As[DD * GROWS];
    int t = threadIdx.x;
    int rowBase = blockIdx.x * GROWS;
    {
        int r = t & 31, kq = t >> 5;
        if (rowBase + r < N) {
            const float4* Av = (const float4*)(out + (size_t)(rowBase + r) * DD);
            #pragma unroll
            for (int q = 0; q < 8; q++) {
                float4 v = Av[kq * 8 + q];
                int k = (kq * 8 + q) * 4;
                As[(k + 0) * GROWS + r] = v.x;
                As[(k + 1) * GROWS + r] = v.y;
                As[(k + 2) * GROWS + r] = v.z;
                As[(k + 3) * GROWS + r] = v.w;
            }
        } else {
            #pragma unroll
            for (int q = 0; q < 8; q++) {
                int k = (kq * 8 + q) * 4;
                As[(k + 0) * GROWS + r] = 0.f;
                As[(k + 1) * GROWS + r] = 0.f;
                As[(k + 2) * GROWS + r] = 0.f;
                As[(k + 3) * GROWS + r] = 0.f;
            }
        }
    }
    int tx = t & 15, ty = t >> 4;
    int c0 = tx * 8, r0 = ty * 4;
    float acc[4][8];
    #pragma unroll
    for (int i = 0; i < 4; i++)
        #pragma unroll
        for (int j = 0; j < 8; j++) acc[i][j] = 0.f;
    for (int kk = 0; kk < DD; kk += 64) {
        __syncthreads();
        const float4* Wv = (const float4*)(Wm + (size_t)kk * DD);
        #pragma unroll
        for (int i = 0; i < 16; i++) ((float4*)Ws)[t + i * 128] = Wv[t + i * 128];
        __syncthreads();
        #pragma unroll 4
        for (int k = 0; k < 64; k++) {
            const float4 a = *(const float4*)&As[(kk + k) * GROWS + r0];
            const float4 w0 = *(const float4*)&Ws[k * DD + c0];
            const float4 w1 = *(const float4*)&Ws[k * DD + c0 + 4];
            const float av[4] = {a.x, a.y, a.z, a.w};
            const float wv[8] = {w0.x, w0.y, w0.z, w0.w, w1.x, w1.y, w1.z, w1.w};
            #pragma unroll
            for (int i = 0; i < 4; i++)
                #pragma unroll
                for (int j = 0; j < 8; j++) acc[i][j] = fmaf(av[i], wv[j], acc[i][j]);
        }
    }
    float bv[8];
    {
        float4 b0 = *(const float4*)&bb[c0];
        float4 b1 = *(const float4*)&bb[c0 + 4];
        bv[0] = b0.x; bv[1] = b0.y; bv[2] = b0.z; bv[3] = b0.w;
        bv[4] = b1.x; bv[5] = b1.y; bv[6] = b1.z; bv[7] = b1.w;
    }
    #pragma unroll
    for (int i = 0; i < 4; i++) {
        int row = rowBase + r0 + i;
        if (row < N) {
            const float4 xv0 = *(const float4*)&x[(size_t)row * DD + c0];
            const float4 xv1 = *(const float4*)&x[(size_t)row * DD + c0 + 4];
            float4 o0, o1;
            o0.x = fmaxf(acc[i][0] + bv[0], 0.f) + xv0.x;
            o0.y = fmaxf(acc[i][1] + bv[1], 0.f) + xv0.y;
            o0.z = fmaxf(acc[i][2] + bv[2], 0.f) + xv0.z;
            o0.w = fmaxf(acc[i][3] + bv[3], 0.f) + xv0.w;
            o1.x = fmaxf(acc[i][4] + bv[4], 0.f) + xv1.x;
            o1.y = fmaxf(acc[i][5] + bv[5], 0.f) + xv1.y;
            o1.z = fmaxf(acc[i][6] + bv[6], 0.f) + xv1.z;
            o1.w = fmaxf(acc[i][7] + bv[7], 0.f) + xv1.w;
            *(float4*)&out[(size_t)row * DD + c0] = o0;
            *(float4*)&out[(size_t)row * DD + c0 + 4] = o1;
        }
    }
}

extern "C" void kernel_launch(void* const* d_in, const int* in_sizes, int n_in,
                              void* d_out, int out_size, void* d_ws, size_t ws_size,
                              hipStream_t stream) {
    const float* x = (const float*)d_in[0];
    const float* W = (const float*)d_in[1];
    const float* b = (const float*)d_in[2];
    const int*   ei = (const int*)d_in[3];
    int N = in_sizes[0] / DD;
    int E = in_sizes[3] / 2;
    float* out = (float*)d_out;
    float* outTail = out + (size_t)N * DD;

    int NB = (N + 511) >> BSH;          // buckets of 512 nodes
    int nA = (E + EPB - 1) / EPB;       // A-pass blocks

    // new-path workspace layout
    char* wsb = (char*)d_ws;
    size_t off = 0;
    unsigned* brec = (unsigned*)(wsb + off);  off += (size_t)E * 4;
    unsigned* recs = (unsigned*)(wsb + off);  off += (size_t)E * 4;
    unsigned* xs   = (unsigned*)(wsb + off);  off += (size_t)N * 64 * 4;
    unsigned* aggh = (unsigned*)(wsb + off);  off += (size_t)N * 64 * 4;
    ushort*   Wt   = (ushort*)(wsb + off);    off += (size_t)DD * DD * 2;
    int* H         = (int*)(wsb + off);       off += (size_t)nA * NB * 4;
    int* bucketstart = (int*)(wsb + off);     off += (size_t)(NB + 1) * 4;
    int* colsum    = (int*)(wsb + off);       off += (size_t)NB * 4;
    int* rowstart  = (int*)(wsb + off);       off += (size_t)(N + 1) * 4;
    float* invs    = (float*)(wsb + off);     off += (size_t)N * 4;
    int* flag      = (int*)(wsb + off);       off += 64;

    bool newpath = (ws_size >= off) && (NB <= 256) && (nA <= 256) && (N <= 131072);

    if (newpath) {
        k_sniff<<<1, 1024, 0, stream>>>(ei, 1024, flag);
        kA1<<<nA, 256, 0, stream>>>(ei, E, NB, outTail, H, flag);
        k_scanH1<<<NB, 256, 0, stream>>>(H, nA, NB, colsum);
        k_scanH2<<<1, 256, 0, stream>>>(colsum, NB, E, bucketstart);
        kA2<<<nA, 256, 0, stream>>>(ei, E, NB, H, bucketstart, brec, flag);
        kB<<<NB, 256, 0, stream>>>(brec, bucketstart, NB, N, E, recs, rowstart, invs);
        int n2 = N * 64;
        k_cvt_xs<<<(n2 + 255) / 256, 256, 0, stream>>>((const float2*)x, invs, xs, n2);
        k_cvt_W<<<(DD * DD + 255) / 256, 256, 0, stream>>>(W, Wt);
        k_agg_s<<<(N + 3) / 4, 256, 0, stream>>>(xs, rowstart, invs, recs, N, aggh);
        k_gemm_mfma<<<(N + 63) / 64, 256, 0, stream>>>((const ushort*)aggh, Wt, b, x, out, N);
    } else {
        // fallback: round-4 rank-based build + f32 compute (known good)
        off = 0;
        unsigned* recsF = (unsigned*)(wsb + off);  off += (size_t)E * 4;
        unsigned* rank  = (unsigned*)(wsb + off);  off += (size_t)E * 4;
        int* cnt        = (int*)(wsb + off);       off += (size_t)N * 4;
        int* rowstartF  = (int*)(wsb + off);       off += (size_t)(N + 1) * 4;
        float* invsF    = (float*)(wsb + off);     off += (size_t)N * 4;
        int* bsum       = (int*)(wsb + off);       off += 512 * 4;
        int* boff       = (int*)(wsb + off);       off += 512 * 4;
        int* flagF      = (int*)(wsb + off);

        hipMemsetAsync(cnt, 0, sizeof(int) * (size_t)N, stream);
        k_sniff<<<1, 1024, 0, stream>>>(ei, 1024, flagF);
        k_count_echo<<<(E + 255) / 256, 256, 0, stream>>>(ei, E, cnt, outTail, rank, flagF);
        int nblk = (N + 1023) / 1024;
        k_scan1<<<nblk, 1024, 0, stream>>>(cnt, N, rowstartF, bsum);
        k_scan2<<<1, 128, 0, stream>>>(bsum, nblk, boff);
        k_scan3<<<(N + 255) / 256, 256, 0, stream>>>(N, E, rowstartF, boff, cnt, invsF);
        k_fill_r<<<(E + 255) / 256, 256, 0, stream>>>(ei, E, rowstartF, rank, recsF, flagF);
        k_agg_f32<<<(N + 3) / 4, 256, 0, stream>>>(x, rowstartF, invsF, recsF, N, out);
        k_gemm_f32<<<(N + GROWS - 1) / GROWS, 128, 0, stream>>>(out, W, b, x, N);
    }
}

// Round 7
// 199.860 us; speedup vs baseline: 1.3681x; 1.0314x over previous
//
#include <hip/hip_runtime.h>

// GCNBlock: out0 = relu( (D^-1/2 (A+I) D^-1/2) (x W) + b ) + x   [N,128] f32
//           out1 = edge_index echoed (as float values) appended in d_out
// Identity: Agg(xW) = Agg(x) W.
// Round 7: EPB 8192->2048 (kA1/kA2 were 196 blocks = 1 wave/SIMD, latency-
// starved); scanH1 generalized to nA<=1024; agg gets 16-deep gather unroll.

#define DD 128
#define EPB 2048      // edges per A-block (8 iters x 256 threads)
#define BSH 9         // bucket shift: 512 nodes per bucket
typedef __attribute__((ext_vector_type(8))) short bf16x8;
typedef __attribute__((ext_vector_type(4))) float f32x4;

__device__ __forceinline__ ushort f2bf(float f) {
    unsigned u = __float_as_uint(f);
    unsigned r = (u + 0x7fffu + ((u >> 16) & 1u)) >> 16;  // RNE
    return (ushort)r;
}
__device__ __forceinline__ float bflo(unsigned u) { return __uint_as_float(u << 16); }
__device__ __forceinline__ float bfhi(unsigned u) { return __uint_as_float(u & 0xffff0000u); }

// ---------- dtype sniff: int64 edge data has all-zero high words ----------
__global__ void k_sniff(const int* __restrict__ p, int n_check, int* __restrict__ flag) {
    __shared__ int any_nonzero;
    if (threadIdx.x == 0) any_nonzero = 0;
    __syncthreads();
    int j = threadIdx.x;
    if (j < n_check && p[2 * j + 1] != 0) any_nonzero = 1;
    __syncthreads();
    if (threadIdx.x == 0) *flag = any_nonzero ? 0 : 1;  // 1 => int64 layout
}

__device__ __forceinline__ int ld_src(const int* p, int e, int E, int is64) {
    return is64 ? p[2 * e] : p[e];
}
__device__ __forceinline__ int ld_dst(const int* p, int e, int E, int is64) {
    return is64 ? p[2 * (E + e)] : p[E + e];
}

// ---------- A1: bucket histogram + fused echo (no global atomics) ----------
__global__ __launch_bounds__(256) void kA1(const int* __restrict__ ei, int E, int NB,
                                           float* __restrict__ outTail, int* __restrict__ H,
                                           const int* __restrict__ flagp) {
    __shared__ int hist[256];
    int is64 = *flagp;
    int t = threadIdx.x, a = blockIdx.x;
    if (t < NB) hist[t] = 0;
    __syncthreads();
    int base = a * EPB;
    #pragma unroll
    for (int it = 0; it < EPB / 256; ++it) {
        int e = base + it * 256 + t;
        if (e < E) {
            int s = ld_src(ei, e, E, is64);
            int d = ld_dst(ei, e, E, is64);
            outTail[e] = (float)s;
            outTail[E + e] = (float)d;
            atomicAdd(&hist[d >> BSH], 1);
        }
    }
    __syncthreads();
    if (t < NB) H[a * NB + t] = hist[t];
}

// ---------- scanH1: per-column exclusive scan of H (NB blocks, nA<=1024) ----------
__global__ __launch_bounds__(256) void k_scanH1(int* __restrict__ H, int nA, int NB,
                                                int* __restrict__ colsum) {
    __shared__ int s[256];
    int b = blockIdx.x, t = threadIdx.x;
    int K = (nA + 255) / 256;
    int base = t * K;
    int local = 0;
    for (int j = 0; j < K; ++j) {
        int a = base + j;
        if (a < nA) local += H[a * NB + b];
    }
    s[t] = local;
    __syncthreads();
    #pragma unroll
    for (int off = 1; off < 256; off <<= 1) {
        int u = (t >= off) ? s[t - off] : 0;
        __syncthreads();
        s[t] += u;
        __syncthreads();
    }
    int run = s[t] - local;  // exclusive prefix of this thread's chunk
    for (int j = 0; j < K; ++j) {
        int a = base + j;
        if (a < nA) { int v = H[a * NB + b]; H[a * NB + b] = run; run += v; }
    }
    if (t == 255) colsum[b] = s[255];
}

// ---------- scanH2: exclusive scan of colsum -> bucketstart (1 block) ----------
__global__ __launch_bounds__(256) void k_scanH2(const int* __restrict__ colsum, int NB, int E,
                                                int* __restrict__ bucketstart) {
    __shared__ int s[256];
    int t = threadIdx.x;
    int v = (t < NB) ? colsum[t] : 0;
    s[t] = v;
    __syncthreads();
    #pragma unroll
    for (int off = 1; off < 256; off <<= 1) {
        int u = (t >= off) ? s[t - off] : 0;
        __syncthreads();
        s[t] += u;
        __syncthreads();
    }
    if (t < NB) bucketstart[t] = s[t] - v;
    if (t == 0) bucketstart[NB] = E;
}

// ---------- A2: scatter packed records to bucket-contiguous brec ----------
// record = src | (dst&511)<<17   (needs N <= 131072)
__global__ __launch_bounds__(256) void kA2(const int* __restrict__ ei, int E, int NB,
                                           const int* __restrict__ H,
                                           const int* __restrict__ bucketstart,
                                           unsigned* __restrict__ brec,
                                           const int* __restrict__ flagp) {
    __shared__ int cur[256];
    int is64 = *flagp;
    int t = threadIdx.x, a = blockIdx.x;
    if (t < NB) cur[t] = H[a * NB + t] + bucketstart[t];
    __syncthreads();
    int base = a * EPB;
    #pragma unroll
    for (int it = 0; it < EPB / 256; ++it) {
        int e = base + it * 256 + t;
        if (e < E) {
            int s = ld_src(ei, e, E, is64);
            int d = ld_dst(ei, e, E, is64);
            int pos = atomicAdd(&cur[d >> BSH], 1);  // LDS atomic
            brec[pos] = (unsigned)s | ((unsigned)(d & 511) << 17);
        }
    }
}

// ---------- B: per-bucket CSR finalize: recs + rowstart + invs ----------
__global__ __launch_bounds__(256) void kB(const unsigned* __restrict__ brec,
                                          const int* __restrict__ bucketstart, int NB, int N,
                                          int E, unsigned* __restrict__ recs,
                                          int* __restrict__ rowstart, float* __restrict__ invs) {
    __shared__ int hist[512];
    __shared__ int scan[513];
    __shared__ int cur[512];
    int b = blockIdx.x, t = threadIdx.x;
    int lo = bucketstart[b], hi = bucketstart[b + 1];
    hist[t] = 0; hist[t + 256] = 0;
    __syncthreads();
    for (int i = lo + t; i < hi; i += 256) atomicAdd(&hist[brec[i] >> 17], 1);
    __syncthreads();
    if (t == 0) {
        int acc = 0;
        for (int j = 0; j < 512; ++j) { scan[j] = acc; acc += hist[j]; }
        scan[512] = acc;
    }
    __syncthreads();
    int nodeBase = b << BSH;
    #pragma unroll
    for (int j = t; j < 512; j += 256) {
        int node = nodeBase + j;
        if (node < N) {
            rowstart[node] = lo + scan[j];
            invs[node] = rsqrtf((float)(1 + hist[j]));  // deg includes self-loop
        }
        cur[j] = lo + scan[j];
    }
    if (b == NB - 1 && t == 0) rowstart[N] = E;
    __syncthreads();
    for (int i = lo + t; i < hi; i += 256) {
        unsigned r = brec[i];
        int pos = atomicAdd(&cur[r >> 17], 1);  // LDS atomic
        recs[pos] = r & 0x1FFFFu;
    }
}

// ---------- convert x -> bf16 pre-scaled by invs: xs[i] = bf16(invs[node]*x[i]) ----------
__global__ void k_cvt_xs(const float2* __restrict__ x2, const float* __restrict__ invs,
                         unsigned* __restrict__ xs, int n2) {
    int i = blockIdx.x * blockDim.x + threadIdx.x;
    if (i < n2) {
        float w = invs[i >> 6];
        float2 v = x2[i];
        xs[i] = (unsigned)f2bf(w * v.x) | ((unsigned)f2bf(w * v.y) << 16);
    }
}

// ---------- convert W -> bf16 transposed: Wt[c][k] = bf16(W[k][c]) ----------
__global__ void k_cvt_W(const float* __restrict__ W, ushort* __restrict__ Wt) {
    int i = blockIdx.x * blockDim.x + threadIdx.x;
    if (i < DD * DD) {
        int c = i >> 7, k = i & 127;
        Wt[i] = f2bf(W[k * DD + c]);
    }
}

// ---------- aggregation: 1 wave/node; deep-unrolled gather of pre-scaled bf16 rows ----------
__global__ void k_agg_s(const unsigned* __restrict__ xs, const int* __restrict__ rowstart,
                        const float* __restrict__ invs, const unsigned* __restrict__ recs,
                        int N, unsigned* __restrict__ aggh) {
    int node = blockIdx.x * 4 + (threadIdx.x >> 6);
    int lane = threadIdx.x & 63;
    if (node >= N) return;
    float wn = invs[node];
    unsigned us = xs[(size_t)node * 64 + lane];  // self: xs[node]*wn = invs^2 * x
    float accx = bflo(us), accy = bfhi(us);
    int e = rowstart[node], e1 = rowstart[node + 1];
    for (; e + 16 <= e1; e += 16) {
        unsigned sv[16], vv[16];
        #pragma unroll
        for (int j = 0; j < 16; ++j) sv[j] = recs[e + j];
        #pragma unroll
        for (int j = 0; j < 16; ++j) vv[j] = xs[(size_t)sv[j] * 64 + lane];
        #pragma unroll
        for (int j = 0; j < 16; ++j) { accx += bflo(vv[j]); accy += bfhi(vv[j]); }
    }
    if (e + 8 <= e1) {
        unsigned sv[8], vv[8];
        #pragma unroll
        for (int j = 0; j < 8; ++j) sv[j] = recs[e + j];
        #pragma unroll
        for (int j = 0; j < 8; ++j) vv[j] = xs[(size_t)sv[j] * 64 + lane];
        #pragma unroll
        for (int j = 0; j < 8; ++j) { accx += bflo(vv[j]); accy += bfhi(vv[j]); }
        e += 8;
    }
    for (; e < e1; ++e) {
        unsigned v0 = xs[(size_t)recs[e] * 64 + lane];
        accx += bflo(v0); accy += bfhi(v0);
    }
    float ox = accx * wn, oy = accy * wn;
    aggh[(size_t)node * 64 + lane] = (unsigned)f2bf(ox) | ((unsigned)f2bf(oy) << 16);
}

// ---------- MFMA GEMM + bias + relu + residual ----------
// A frag: row=lane&15, k=(lane>>4)*8+j (contig, aggh row-major)
// B frag: col=lane&15, k=(lane>>4)*8+j (contig, Wt[c][k])
// C/D:    col=lane&15, row=(lane>>4)*4+reg   [m89-verified]
__global__ __launch_bounds__(256) void k_gemm_mfma(const ushort* __restrict__ aggh,
                                                   const ushort* __restrict__ Wt,
                                                   const float* __restrict__ bb,
                                                   const float* __restrict__ x,
                                                   float* __restrict__ out, int N) {
    int wave = threadIdx.x >> 6, lane = threadIdx.x & 63;
    int rowBase = blockIdx.x * 64 + wave * 16;
    int rfrag = lane & 15, kgrp = lane >> 4;
    f32x4 zero = {0.f, 0.f, 0.f, 0.f};
    f32x4 acc[8];
    #pragma unroll
    for (int n = 0; n < 8; ++n) acc[n] = zero;

    int arow = rowBase + rfrag;
    bool av = arow < N;
    const ushort* abase = aggh + (size_t)(av ? arow : 0) * DD + kgrp * 8;
    const ushort* bbase = Wt + rfrag * DD + kgrp * 8;

    #pragma unroll
    for (int ks = 0; ks < 4; ++ks) {
        bf16x8 a = {0, 0, 0, 0, 0, 0, 0, 0};
        if (av) a = *(const bf16x8*)(abase + ks * 32);
        #pragma unroll
        for (int n = 0; n < 8; ++n) {
            bf16x8 bf = *(const bf16x8*)(bbase + n * 16 * DD + ks * 32);
            acc[n] = __builtin_amdgcn_mfma_f32_16x16x32_bf16(a, bf, acc[n], 0, 0, 0);
        }
    }

    int colb = lane & 15, rq = lane >> 4;
    #pragma unroll
    for (int n = 0; n < 8; ++n) {
        int col = n * 16 + colb;
        float bias = bb[col];
        #pragma unroll
        for (int j = 0; j < 4; ++j) {
            int row = rowBase + rq * 4 + j;
            if (row < N) {
                size_t o = (size_t)row * DD + col;
                out[o] = fmaxf(acc[n][j] + bias, 0.f) + x[o];
            }
        }
    }
}

// =================== fallback path (shape/ws outside new-path limits) ===================
__global__ void k_count_echo(const int* __restrict__ ei, int E, int* __restrict__ cnt,
                             float* __restrict__ outTail, unsigned* __restrict__ rank,
                             const int* __restrict__ flagp) {
    int is64 = *flagp;
    int e = blockIdx.x * blockDim.x + threadIdx.x;
    if (e < E) {
        int s = ld_src(ei, e, E, is64);
        int d = ld_dst(ei, e, E, is64);
        outTail[e] = (float)s;
        outTail[E + e] = (float)d;
        rank[e] = (unsigned)atomicAdd(&cnt[d], 1);
    }
}

__global__ void k_scan1(const int* __restrict__ cnt, int N, int* __restrict__ rowstart,
                        int* __restrict__ bsum) {
    __shared__ int s[1024];
    int tid = threadIdx.x;
    int i = blockIdx.x * 1024 + tid;
    int v = (i < N) ? cnt[i] : 0;
    s[tid] = v;
    __syncthreads();
    for (int off = 1; off < 1024; off <<= 1) {
        int t2 = (tid >= off) ? s[tid - off] : 0;
        __syncthreads();
        s[tid] += t2;
        __syncthreads();
    }
    if (i < N) rowstart[i] = s[tid] - v;
    if (tid == 1023) bsum[blockIdx.x] = s[1023];
}

__global__ void k_scan2(const int* __restrict__ bsum, int nblk, int* __restrict__ boff) {
    __shared__ int s[128];
    int t = threadIdx.x;
    if (t < nblk) s[t] = bsum[t];
    __syncthreads();
    if (t == 0) {
        int a = 0;
        for (int i = 0; i < nblk; i++) { int v = s[i]; s[i] = a; a += v; }
    }
    __syncthreads();
    if (t < nblk) boff[t] = s[t];
}

__global__ void k_scan3(int N, int E, int* __restrict__ rowstart, const int* __restrict__ boff,
                        const int* __restrict__ cnt, float* __restrict__ invs) {
    int i = blockIdx.x * blockDim.x + threadIdx.x;
    if (i < N) {
        int r = rowstart[i] + boff[i >> 10];
        rowstart[i] = r;
        invs[i] = rsqrtf((float)(1 + cnt[i]));
    }
    if (i == 0 && blockIdx.x == 0) rowstart[N] = E;
}

__global__ void k_fill_r(const int* __restrict__ ei, int E, const int* __restrict__ rowstart,
                         const unsigned* __restrict__ rank, unsigned* __restrict__ recs,
                         const int* __restrict__ flagp) {
    int is64 = *flagp;
    int e = blockIdx.x * blockDim.x + threadIdx.x;
    if (e < E) {
        int d = ld_dst(ei, e, E, is64);
        int s = ld_src(ei, e, E, is64);
        recs[rowstart[d] + rank[e]] = (unsigned)s;
    }
}

__global__ void k_agg_f32(const float* __restrict__ x, const int* __restrict__ rowstart,
                          const float* __restrict__ invs, const unsigned* __restrict__ recs,
                          int N, float* __restrict__ aggOut) {
    int node = blockIdx.x * 4 + (threadIdx.x >> 6);
    int lane = threadIdx.x & 63;
    if (node >= N) return;
    const float2* xr = (const float2*)x;
    float wn = invs[node];
    float2 xself = xr[(size_t)node * 64 + lane];
    float accx = wn * xself.x, accy = wn * xself.y;
    int e = rowstart[node], e1 = rowstart[node + 1];
    for (; e < e1; ++e) {
        unsigned s = recs[e];
        float w = invs[s];
        float2 v = xr[(size_t)s * 64 + lane];
        accx = fmaf(w, v.x, accx); accy = fmaf(w, v.y, accy);
    }
    float2 o; o.x = accx * wn; o.y = accy * wn;
    ((float2*)aggOut)[(size_t)node * 64 + lane] = o;
}

#define GROWS 32
__global__ __launch_bounds__(128) void k_gemm_f32(float* __restrict__ out, const float* __restrict__ Wm,
                                                  const float* __restrict__ bb,
                                                  const float* __restrict__ x, int N) {
    __shared__ float Ws[64 * DD];
    __shared__ float As[DD * GROWS];
    int t = threadIdx.x;
    int rowBase = blockIdx.x * GROWS;
    {
        int r = t & 31, kq = t >> 5;
        if (rowBase + r < N) {
            const float4* Av = (const float4*)(out + (size_t)(rowBase + r) * DD);
            #pragma unroll
            for (int q = 0; q < 8; q++) {
                float4 v = Av[kq * 8 + q];
                int k = (kq * 8 + q) * 4;
                As[(k + 0) * GROWS + r] = v.x;
                As[(k + 1) * GROWS + r] = v.y;
                As[(k + 2) * GROWS + r] = v.z;
                As[(k + 3) * GROWS + r] = v.w;
            }
        } else {
            #pragma unroll
            for (int q = 0; q < 8; q++) {
                int k = (kq * 8 + q) * 4;
                As[(k + 0) * GROWS + r] = 0.f;
                As[(k + 1) * GROWS + r] = 0.f;
                As[(k + 2) * GROWS + r] = 0.f;
                As[(k + 3) * GROWS + r] = 0.f;
            }
        }
    }
    int tx = t & 15, ty = t >> 4;
    int c0 = tx * 8, r0 = ty * 4;
    float acc[4][8];
    #pragma unroll
    for (int i = 0; i < 4; i++)
        #pragma unroll
        for (int j = 0; j < 8; j++) acc[i][j] = 0.f;
    for (int kk = 0; kk < DD; kk += 64) {
        __syncthreads();
        const float4* Wv = (const float4*)(Wm + (size_t)kk * DD);
        #pragma unroll
        for (int i = 0; i < 16; i++) ((float4*)Ws)[t + i * 128] = Wv[t + i * 128];
        __syncthreads();
        #pragma unroll 4
        for (int k = 0; k < 64; k++) {
            const float4 a = *(const float4*)&As[(kk + k) * GROWS + r0];
            const float4 w0 = *(const float4*)&Ws[k * DD + c0];
            const float4 w1 = *(const float4*)&Ws[k * DD + c0 + 4];
            const float av[4] = {a.x, a.y, a.z, a.w};
            const float wv[8] = {w0.x, w0.y, w0.z, w0.w, w1.x, w1.y, w1.z, w1.w};
            #pragma unroll
            for (int i = 0; i < 4; i++)
                #pragma unroll
                for (int j = 0; j < 8; j++) acc[i][j] = fmaf(av[i], wv[j], acc[i][j]);
        }
    }
    float bv[8];
    {
        float4 b0 = *(const float4*)&bb[c0];
        float4 b1 = *(const float4*)&bb[c0 + 4];
        bv[0] = b0.x; bv[1] = b0.y; bv[2] = b0.z; bv[3] = b0.w;
        bv[4] = b1.x; bv[5] = b1.y; bv[6] = b1.z; bv[7] = b1.w;
    }
    #pragma unroll
    for (int i = 0; i < 4; i++) {
        int row = rowBase + r0 + i;
        if (row < N) {
            const float4 xv0 = *(const float4*)&x[(size_t)row * DD + c0];
            const float4 xv1 = *(const float4*)&x[(size_t)row * DD + c0 + 4];
            float4 o0, o1;
            o0.x = fmaxf(acc[i][0] + bv[0], 0.f) + xv0.x;
            o0.y = fmaxf(acc[i][1] + bv[1], 0.f) + xv0.y;
            o0.z = fmaxf(acc[i][2] + bv[2], 0.f) + xv0.z;
            o0.w = fmaxf(acc[i][3] + bv[3], 0.f) + xv0.w;
            o1.x = fmaxf(acc[i][4] + bv[4], 0.f) + xv1.x;
            o1.y = fmaxf(acc[i][5] + bv[5], 0.f) + xv1.y;
            o1.z = fmaxf(acc[i][6] + bv[6], 0.f) + xv1.z;
            o1.w = fmaxf(acc[i][7] + bv[7], 0.f) + xv1.w;
            *(float4*)&out[(size_t)row * DD + c0] = o0;
            *(float4*)&out[(size_t)row * DD + c0 + 4] = o1;
        }
    }
}

extern "C" void kernel_launch(void* const* d_in, const int* in_sizes, int n_in,
                              void* d_out, int out_size, void* d_ws, size_t ws_size,
                              hipStream_t stream) {
    const float* x = (const float*)d_in[0];
    const float* W = (const float*)d_in[1];
    const float* b = (const float*)d_in[2];
    const int*   ei = (const int*)d_in[3];
    int N = in_sizes[0] / DD;
    int E = in_sizes[3] / 2;
    float* out = (float*)d_out;
    float* outTail = out + (size_t)N * DD;

    int NB = (N + 511) >> BSH;          // buckets of 512 nodes
    int nA = (E + EPB - 1) / EPB;       // A-pass blocks

    // new-path workspace layout
    char* wsb = (char*)d_ws;
    size_t off = 0;
    unsigned* brec = (unsigned*)(wsb + off);  off += (size_t)E * 4;
    unsigned* recs = (unsigned*)(wsb + off);  off += (size_t)E * 4;
    unsigned* xs   = (unsigned*)(wsb + off);  off += (size_t)N * 64 * 4;
    unsigned* aggh = (unsigned*)(wsb + off);  off += (size_t)N * 64 * 4;
    ushort*   Wt   = (ushort*)(wsb + off);    off += (size_t)DD * DD * 2;
    int* H         = (int*)(wsb + off);       off += (size_t)nA * NB * 4;
    int* bucketstart = (int*)(wsb + off);     off += (size_t)(NB + 1) * 4;
    int* colsum    = (int*)(wsb + off);       off += (size_t)NB * 4;
    int* rowstart  = (int*)(wsb + off);       off += (size_t)(N + 1) * 4;
    float* invs    = (float*)(wsb + off);     off += (size_t)N * 4;
    int* flag      = (int*)(wsb + off);       off += 64;

    bool newpath = (ws_size >= off) && (NB <= 256) && (nA <= 1024) && (N <= 131072);

    if (newpath) {
        k_sniff<<<1, 1024, 0, stream>>>(ei, 1024, flag);
        kA1<<<nA, 256, 0, stream>>>(ei, E, NB, outTail, H, flag);
        k_scanH1<<<NB, 256, 0, stream>>>(H, nA, NB, colsum);
        k_scanH2<<<1, 256, 0, stream>>>(colsum, NB, E, bucketstart);
        kA2<<<nA, 256, 0, stream>>>(ei, E, NB, H, bucketstart, brec, flag);
        kB<<<NB, 256, 0, stream>>>(brec, bucketstart, NB, N, E, recs, rowstart, invs);
        int n2 = N * 64;
        k_cvt_xs<<<(n2 + 255) / 256, 256, 0, stream>>>((const float2*)x, invs, xs, n2);
        k_cvt_W<<<(DD * DD + 255) / 256, 256, 0, stream>>>(W, Wt);
        k_agg_s<<<(N + 3) / 4, 256, 0, stream>>>(xs, rowstart, invs, recs, N, aggh);
        k_gemm_mfma<<<(N + 63) / 64, 256, 0, stream>>>((const ushort*)aggh, Wt, b, x, out, N);
    } else {
        // fallback: round-4 rank-based build + f32 compute (known good)
        off = 0;
        unsigned* recsF = (unsigned*)(wsb + off);  off += (size_t)E * 4;
        unsigned* rank  = (unsigned*)(wsb + off);  off += (size_t)E * 4;
        int* cnt        = (int*)(wsb + off);       off += (size_t)N * 4;
        int* rowstartF  = (int*)(wsb + off);       off += (size_t)(N + 1) * 4;
        float* invsF    = (float*)(wsb + off);     off += (size_t)N * 4;
        int* bsum       = (int*)(wsb + off);       off += 512 * 4;
        int* boff       = (int*)(wsb + off);       off += 512 * 4;
        int* flagF      = (int*)(wsb + off);

        hipMemsetAsync(cnt, 0, sizeof(int) * (size_t)N, stream);
        k_sniff<<<1, 1024, 0, stream>>>(ei, 1024, flagF);
        k_count_echo<<<(E + 255) / 256, 256, 0, stream>>>(ei, E, cnt, outTail, rank, flagF);
        int nblk = (N + 1023) / 1024;
        k_scan1<<<nblk, 1024, 0, stream>>>(cnt, N, rowstartF, bsum);
        k_scan2<<<1, 128, 0, stream>>>(bsum, nblk, boff);
        k_scan3<<<(N + 255) / 256, 256, 0, stream>>>(N, E, rowstartF, boff, cnt, invsF);
        k_fill_r<<<(E + 255) / 256, 256, 0, stream>>>(ei, E, rowstartF, rank, recsF, flagF);
        k_agg_f32<<<(N + 3) / 4, 256, 0, stream>>>(x, rowstartF, invsF, recsF, N, out);
        k_gemm_f32<<<(N + GROWS - 1) / GROWS, 128, 0, stream>>>(out, W, b, x, N);
    }
}

// Round 8
// 190.122 us; speedup vs baseline: 1.4381x; 1.0512x over previous
//
#include <hip/hip_runtime.h>

// GCNBlock: out0 = relu( (D^-1/2 (A+I) D^-1/2) (x W) + b ) + x   [N,128] f32
//           out1 = edge_index echoed (as float values) appended in d_out
// Identity: Agg(xW) = Agg(x) W.
// Round 8: swapped-operand MFMA (D = Wt_frag x agg_frag) so each lane's
// f32x4 acc = 4 consecutive output cols of ONE row -> float4 epilogue
// (was 32 scalar reads + 32 scalar writes per lane; 72us gemm).

#define DD 128
#define EPB 2048      // edges per A-block (8 iters x 256 threads)
#define BSH 9         // bucket shift: 512 nodes per bucket
typedef __attribute__((ext_vector_type(8))) short bf16x8;
typedef __attribute__((ext_vector_type(4))) float f32x4;

__device__ __forceinline__ ushort f2bf(float f) {
    unsigned u = __float_as_uint(f);
    unsigned r = (u + 0x7fffu + ((u >> 16) & 1u)) >> 16;  // RNE
    return (ushort)r;
}
__device__ __forceinline__ float bflo(unsigned u) { return __uint_as_float(u << 16); }
__device__ __forceinline__ float bfhi(unsigned u) { return __uint_as_float(u & 0xffff0000u); }

// ---------- dtype sniff: int64 edge data has all-zero high words ----------
__global__ void k_sniff(const int* __restrict__ p, int n_check, int* __restrict__ flag) {
    __shared__ int any_nonzero;
    if (threadIdx.x == 0) any_nonzero = 0;
    __syncthreads();
    int j = threadIdx.x;
    if (j < n_check && p[2 * j + 1] != 0) any_nonzero = 1;
    __syncthreads();
    if (threadIdx.x == 0) *flag = any_nonzero ? 0 : 1;  // 1 => int64 layout
}

__device__ __forceinline__ int ld_src(const int* p, int e, int E, int is64) {
    return is64 ? p[2 * e] : p[e];
}
__device__ __forceinline__ int ld_dst(const int* p, int e, int E, int is64) {
    return is64 ? p[2 * (E + e)] : p[E + e];
}

// ---------- A1: bucket histogram + fused echo (no global atomics) ----------
__global__ __launch_bounds__(256) void kA1(const int* __restrict__ ei, int E, int NB,
                                           float* __restrict__ outTail, int* __restrict__ H,
                                           const int* __restrict__ flagp) {
    __shared__ int hist[256];
    int is64 = *flagp;
    int t = threadIdx.x, a = blockIdx.x;
    if (t < NB) hist[t] = 0;
    __syncthreads();
    int base = a * EPB;
    #pragma unroll
    for (int it = 0; it < EPB / 256; ++it) {
        int e = base + it * 256 + t;
        if (e < E) {
            int s = ld_src(ei, e, E, is64);
            int d = ld_dst(ei, e, E, is64);
            outTail[e] = (float)s;
            outTail[E + e] = (float)d;
            atomicAdd(&hist[d >> BSH], 1);
        }
    }
    __syncthreads();
    if (t < NB) H[a * NB + t] = hist[t];
}

// ---------- scanH1: per-column exclusive scan of H (NB blocks, nA<=1024) ----------
__global__ __launch_bounds__(256) void k_scanH1(int* __restrict__ H, int nA, int NB,
                                                int* __restrict__ colsum) {
    __shared__ int s[256];
    int b = blockIdx.x, t = threadIdx.x;
    int K = (nA + 255) / 256;
    int base = t * K;
    int local = 0;
    for (int j = 0; j < K; ++j) {
        int a = base + j;
        if (a < nA) local += H[a * NB + b];
    }
    s[t] = local;
    __syncthreads();
    #pragma unroll
    for (int off = 1; off < 256; off <<= 1) {
        int u = (t >= off) ? s[t - off] : 0;
        __syncthreads();
        s[t] += u;
        __syncthreads();
    }
    int run = s[t] - local;  // exclusive prefix of this thread's chunk
    for (int j = 0; j < K; ++j) {
        int a = base + j;
        if (a < nA) { int v = H[a * NB + b]; H[a * NB + b] = run; run += v; }
    }
    if (t == 255) colsum[b] = s[255];
}

// ---------- scanH2: exclusive scan of colsum -> bucketstart (1 block) ----------
__global__ __launch_bounds__(256) void k_scanH2(const int* __restrict__ colsum, int NB, int E,
                                                int* __restrict__ bucketstart) {
    __shared__ int s[256];
    int t = threadIdx.x;
    int v = (t < NB) ? colsum[t] : 0;
    s[t] = v;
    __syncthreads();
    #pragma unroll
    for (int off = 1; off < 256; off <<= 1) {
        int u = (t >= off) ? s[t - off] : 0;
        __syncthreads();
        s[t] += u;
        __syncthreads();
    }
    if (t < NB) bucketstart[t] = s[t] - v;
    if (t == 0) bucketstart[NB] = E;
}

// ---------- A2: scatter packed records to bucket-contiguous brec ----------
// record = src | (dst&511)<<17   (needs N <= 131072)
__global__ __launch_bounds__(256) void kA2(const int* __restrict__ ei, int E, int NB,
                                           const int* __restrict__ H,
                                           const int* __restrict__ bucketstart,
                                           unsigned* __restrict__ brec,
                                           const int* __restrict__ flagp) {
    __shared__ int cur[256];
    int is64 = *flagp;
    int t = threadIdx.x, a = blockIdx.x;
    if (t < NB) cur[t] = H[a * NB + t] + bucketstart[t];
    __syncthreads();
    int base = a * EPB;
    #pragma unroll
    for (int it = 0; it < EPB / 256; ++it) {
        int e = base + it * 256 + t;
        if (e < E) {
            int s = ld_src(ei, e, E, is64);
            int d = ld_dst(ei, e, E, is64);
            int pos = atomicAdd(&cur[d >> BSH], 1);  // LDS atomic
            brec[pos] = (unsigned)s | ((unsigned)(d & 511) << 17);
        }
    }
}

// ---------- B: per-bucket CSR finalize: recs + rowstart + invs ----------
__global__ __launch_bounds__(256) void kB(const unsigned* __restrict__ brec,
                                          const int* __restrict__ bucketstart, int NB, int N,
                                          int E, unsigned* __restrict__ recs,
                                          int* __restrict__ rowstart, float* __restrict__ invs) {
    __shared__ int hist[512];
    __shared__ int scan[513];
    __shared__ int cur[512];
    int b = blockIdx.x, t = threadIdx.x;
    int lo = bucketstart[b], hi = bucketstart[b + 1];
    hist[t] = 0; hist[t + 256] = 0;
    __syncthreads();
    for (int i = lo + t; i < hi; i += 256) atomicAdd(&hist[brec[i] >> 17], 1);
    __syncthreads();
    if (t == 0) {
        int acc = 0;
        for (int j = 0; j < 512; ++j) { scan[j] = acc; acc += hist[j]; }
        scan[512] = acc;
    }
    __syncthreads();
    int nodeBase = b << BSH;
    #pragma unroll
    for (int j = t; j < 512; j += 256) {
        int node = nodeBase + j;
        if (node < N) {
            rowstart[node] = lo + scan[j];
            invs[node] = rsqrtf((float)(1 + hist[j]));  // deg includes self-loop
        }
        cur[j] = lo + scan[j];
    }
    if (b == NB - 1 && t == 0) rowstart[N] = E;
    __syncthreads();
    for (int i = lo + t; i < hi; i += 256) {
        unsigned r = brec[i];
        int pos = atomicAdd(&cur[r >> 17], 1);  // LDS atomic
        recs[pos] = r & 0x1FFFFu;
    }
}

// ---------- convert x -> bf16 pre-scaled by invs: xs[i] = bf16(invs[node]*x[i]) ----------
__global__ void k_cvt_xs(const float2* __restrict__ x2, const float* __restrict__ invs,
                         unsigned* __restrict__ xs, int n2) {
    int i = blockIdx.x * blockDim.x + threadIdx.x;
    if (i < n2) {
        float w = invs[i >> 6];
        float2 v = x2[i];
        xs[i] = (unsigned)f2bf(w * v.x) | ((unsigned)f2bf(w * v.y) << 16);
    }
}

// ---------- convert W -> bf16 transposed: Wt[c][k] = bf16(W[k][c]) ----------
__global__ void k_cvt_W(const float* __restrict__ W, ushort* __restrict__ Wt) {
    int i = blockIdx.x * blockDim.x + threadIdx.x;
    if (i < DD * DD) {
        int c = i >> 7, k = i & 127;
        Wt[i] = f2bf(W[k * DD + c]);
    }
}

// ---------- aggregation: 1 wave/node; deep-unrolled gather of pre-scaled bf16 rows ----------
__global__ void k_agg_s(const unsigned* __restrict__ xs, const int* __restrict__ rowstart,
                        const float* __restrict__ invs, const unsigned* __restrict__ recs,
                        int N, unsigned* __restrict__ aggh) {
    int node = blockIdx.x * 4 + (threadIdx.x >> 6);
    int lane = threadIdx.x & 63;
    if (node >= N) return;
    float wn = invs[node];
    unsigned us = xs[(size_t)node * 64 + lane];  // self: xs[node]*wn = invs^2 * x
    float accx = bflo(us), accy = bfhi(us);
    int e = rowstart[node], e1 = rowstart[node + 1];
    for (; e + 16 <= e1; e += 16) {
        unsigned sv[16], vv[16];
        #pragma unroll
        for (int j = 0; j < 16; ++j) sv[j] = recs[e + j];
        #pragma unroll
        for (int j = 0; j < 16; ++j) vv[j] = xs[(size_t)sv[j] * 64 + lane];
        #pragma unroll
        for (int j = 0; j < 16; ++j) { accx += bflo(vv[j]); accy += bfhi(vv[j]); }
    }
    if (e + 8 <= e1) {
        unsigned sv[8], vv[8];
        #pragma unroll
        for (int j = 0; j < 8; ++j) sv[j] = recs[e + j];
        #pragma unroll
        for (int j = 0; j < 8; ++j) vv[j] = xs[(size_t)sv[j] * 64 + lane];
        #pragma unroll
        for (int j = 0; j < 8; ++j) { accx += bflo(vv[j]); accy += bfhi(vv[j]); }
        e += 8;
    }
    for (; e < e1; ++e) {
        unsigned v0 = xs[(size_t)recs[e] * 64 + lane];
        accx += bflo(v0); accy += bfhi(v0);
    }
    float ox = accx * wn, oy = accy * wn;
    aggh[(size_t)node * 64 + lane] = (unsigned)f2bf(ox) | ((unsigned)f2bf(oy) << 16);
}

// ---------- MFMA GEMM + bias + relu + residual (swapped operands) ----------
// D = mfma(A=Wt_frag, B=agg_frag):
//   A frag: m=lane&15 (W col within 16-group), k=(lane>>4)*8+j  -> Wt[c][k] contig
//   B frag: n=lane&15 (node row),             k=(lane>>4)*8+j  -> aggh[r][k] contig
//   C/D:    col=lane&15 -> NODE row; row=(lane>>4)*4+reg -> 4 CONSECUTIVE out cols
// => each lane's f32x4 acc = float4 at out[node][n*16+(lane>>4)*4]
__global__ __launch_bounds__(256) void k_gemm_mfma(const ushort* __restrict__ aggh,
                                                   const ushort* __restrict__ Wt,
                                                   const float* __restrict__ bb,
                                                   const float* __restrict__ x,
                                                   float* __restrict__ out, int N) {
    int wave = threadIdx.x >> 6, lane = threadIdx.x & 63;
    int rowBase = blockIdx.x * 64 + wave * 16;
    int rfrag = lane & 15, kgrp = lane >> 4;
    f32x4 zero = {0.f, 0.f, 0.f, 0.f};
    f32x4 acc[8];
    #pragma unroll
    for (int n = 0; n < 8; ++n) acc[n] = zero;

    int arow = rowBase + rfrag;
    bool av = arow < N;
    const ushort* bbase = aggh + (size_t)(av ? arow : 0) * DD + kgrp * 8;  // B frag (nodes)
    const ushort* wbase = Wt + rfrag * DD + kgrp * 8;                      // A frag (W cols)

    #pragma unroll
    for (int ks = 0; ks < 4; ++ks) {
        bf16x8 bnode = {0, 0, 0, 0, 0, 0, 0, 0};
        if (av) bnode = *(const bf16x8*)(bbase + ks * 32);
        #pragma unroll
        for (int n = 0; n < 8; ++n) {
            bf16x8 aw = *(const bf16x8*)(wbase + n * 16 * DD + ks * 32);
            acc[n] = __builtin_amdgcn_mfma_f32_16x16x32_bf16(aw, bnode, acc[n], 0, 0, 0);
        }
    }

    int node = rowBase + (lane & 15);
    if (node < N) {
        int csub = (lane >> 4) * 4;
        #pragma unroll
        for (int n = 0; n < 8; ++n) {
            int c0 = n * 16 + csub;
            float4 bv = *(const float4*)&bb[c0];
            float4 xv = *(const float4*)&x[(size_t)node * DD + c0];
            float4 o;
            o.x = fmaxf(acc[n][0] + bv.x, 0.f) + xv.x;
            o.y = fmaxf(acc[n][1] + bv.y, 0.f) + xv.y;
            o.z = fmaxf(acc[n][2] + bv.z, 0.f) + xv.z;
            o.w = fmaxf(acc[n][3] + bv.w, 0.f) + xv.w;
            *(float4*)&out[(size_t)node * DD + c0] = o;
        }
    }
}

// =================== fallback path (shape/ws outside new-path limits) ===================
__global__ void k_count_echo(const int* __restrict__ ei, int E, int* __restrict__ cnt,
                             float* __restrict__ outTail, unsigned* __restrict__ rank,
                             const int* __restrict__ flagp) {
    int is64 = *flagp;
    int e = blockIdx.x * blockDim.x + threadIdx.x;
    if (e < E) {
        int s = ld_src(ei, e, E, is64);
        int d = ld_dst(ei, e, E, is64);
        outTail[e] = (float)s;
        outTail[E + e] = (float)d;
        rank[e] = (unsigned)atomicAdd(&cnt[d], 1);
    }
}

__global__ void k_scan1(const int* __restrict__ cnt, int N, int* __restrict__ rowstart,
                        int* __restrict__ bsum) {
    __shared__ int s[1024];
    int tid = threadIdx.x;
    int i = blockIdx.x * 1024 + tid;
    int v = (i < N) ? cnt[i] : 0;
    s[tid] = v;
    __syncthreads();
    for (int off = 1; off < 1024; off <<= 1) {
        int t2 = (tid >= off) ? s[tid - off] : 0;
        __syncthreads();
        s[tid] += t2;
        __syncthreads();
    }
    if (i < N) rowstart[i] = s[tid] - v;
    if (tid == 1023) bsum[blockIdx.x] = s[1023];
}

__global__ void k_scan2(const int* __restrict__ bsum, int nblk, int* __restrict__ boff) {
    __shared__ int s[128];
    int t = threadIdx.x;
    if (t < nblk) s[t] = bsum[t];
    __syncthreads();
    if (t == 0) {
        int a = 0;
        for (int i = 0; i < nblk; i++) { int v = s[i]; s[i] = a; a += v; }
    }
    __syncthreads();
    if (t < nblk) boff[t] = s[t];
}

__global__ void k_scan3(int N, int E, int* __restrict__ rowstart, const int* __restrict__ boff,
                        const int* __restrict__ cnt, float* __restrict__ invs) {
    int i = blockIdx.x * blockDim.x + threadIdx.x;
    if (i < N) {
        int r = rowstart[i] + boff[i >> 10];
        rowstart[i] = r;
        invs[i] = rsqrtf((float)(1 + cnt[i]));
    }
    if (i == 0 && blockIdx.x == 0) rowstart[N] = E;
}

__global__ void k_fill_r(const int* __restrict__ ei, int E, const int* __restrict__ rowstart,
                         const unsigned* __restrict__ rank, unsigned* __restrict__ recs,
                         const int* __restrict__ flagp) {
    int is64 = *flagp;
    int e = blockIdx.x * blockDim.x + threadIdx.x;
    if (e < E) {
        int d = ld_dst(ei, e, E, is64);
        int s = ld_src(ei, e, E, is64);
        recs[rowstart[d] + rank[e]] = (unsigned)s;
    }
}

__global__ void k_agg_f32(const float* __restrict__ x, const int* __restrict__ rowstart,
                          const float* __restrict__ invs, const unsigned* __restrict__ recs,
                          int N, float* __restrict__ aggOut) {
    int node = blockIdx.x * 4 + (threadIdx.x >> 6);
    int lane = threadIdx.x & 63;
    if (node >= N) return;
    const float2* xr = (const float2*)x;
    float wn = invs[node];
    float2 xself = xr[(size_t)node * 64 + lane];
    float accx = wn * xself.x, accy = wn * xself.y;
    int e = rowstart[node], e1 = rowstart[node + 1];
    for (; e < e1; ++e) {
        unsigned s = recs[e];
        float w = invs[s];
        float2 v = xr[(size_t)s * 64 + lane];
        accx = fmaf(w, v.x, accx); accy = fmaf(w, v.y, accy);
    }
    float2 o; o.x = accx * wn; o.y = accy * wn;
    ((float2*)aggOut)[(size_t)node * 64 + lane] = o;
}

#define GROWS 32
__global__ __launch_bounds__(128) void k_gemm_f32(float* __restrict__ out, const float* __restrict__ Wm,
                                                  const float* __restrict__ bb,
                                                  const float* __restrict__ x, int N) {
    __shared__ float Ws[64 * DD];
    __shared__ float As[DD * GROWS];
    int t = threadIdx.x;
    int rowBase = blockIdx.x * GROWS;
    {
        int r = t & 31, kq = t >> 5;
        if (rowBase + r < N) {
            const float4* Av = (const float4*)(out + (size_t)(rowBase + r) * DD);
            #pragma unroll
            for (int q = 0; q < 8; q++) {
                float4 v = Av[kq * 8 + q];
                int k = (kq * 8 + q) * 4;
                As[(k + 0) * GROWS + r] = v.x;
                As[(k + 1) * GROWS + r] = v.y;
                As[(k + 2) * GROWS + r] = v.z;
                As[(k + 3) * GROWS + r] = v.w;
            }
        } else {
            #pragma unroll
            for (int q = 0; q < 8; q++) {
                int k = (kq * 8 + q) * 4;
                As[(k + 0) * GROWS + r] = 0.f;
                As[(k + 1) * GROWS + r] = 0.f;
                As[(k + 2) * GROWS + r] = 0.f;
                As[(k + 3) * GROWS + r] = 0.f;
            }
        }
    }
    int tx = t & 15, ty = t >> 4;
    int c0 = tx * 8, r0 = ty * 4;
    float acc[4][8];
    #pragma unroll
    for (int i = 0; i < 4; i++)
        #pragma unroll
        for (int j = 0; j < 8; j++) acc[i][j] = 0.f;
    for (int kk = 0; kk < DD; kk += 64) {
        __syncthreads();
        const float4* Wv = (const float4*)(Wm + (size_t)kk * DD);
        #pragma unroll
        for (int i = 0; i < 16; i++) ((float4*)Ws)[t + i * 128] = Wv[t + i * 128];
        __syncthreads();
        #pragma unroll 4
        for (int k = 0; k < 64; k++) {
            const float4 a = *(const float4*)&As[(kk + k) * GROWS + r0];
            const float4 w0 = *(const float4*)&Ws[k * DD + c0];
            const float4 w1 = *(const float4*)&Ws[k * DD + c0 + 4];
            const float av[4] = {a.x, a.y, a.z, a.w};
            const float wv[8] = {w0.x, w0.y, w0.z, w0.w, w1.x, w1.y, w1.z, w1.w};
            #pragma unroll
            for (int i = 0; i < 4; i++)
                #pragma unroll
                for (int j = 0; j < 8; j++) acc[i][j] = fmaf(av[i], wv[j], acc[i][j]);
        }
    }
    float bv[8];
    {
        float4 b0 = *(const float4*)&bb[c0];
        float4 b1 = *(const float4*)&bb[c0 + 4];
        bv[0] = b0.x; bv[1] = b0.y; bv[2] = b0.z; bv[3] = b0.w;
        bv[4] = b1.x; bv[5] = b1.y; bv[6] = b1.z; bv[7] = b1.w;
    }
    #pragma unroll
    for (int i = 0; i < 4; i++) {
        int row = rowBase + r0 + i;
        if (row < N) {
            const float4 xv0 = *(const float4*)&x[(size_t)row * DD + c0];
            const float4 xv1 = *(const float4*)&x[(size_t)row * DD + c0 + 4];
            float4 o0, o1;
            o0.x = fmaxf(acc[i][0] + bv[0], 0.f) + xv0.x;
            o0.y = fmaxf(acc[i][1] + bv[1], 0.f) + xv0.y;
            o0.z = fmaxf(acc[i][2] + bv[2], 0.f) + xv0.z;
            o0.w = fmaxf(acc[i][3] + bv[3], 0.f) + xv0.w;
            o1.x = fmaxf(acc[i][4] + bv[4], 0.f) + xv1.x;
            o1.y = fmaxf(acc[i][5] + bv[5], 0.f) + xv1.y;
            o1.z = fmaxf(acc[i][6] + bv[6], 0.f) + xv1.z;
            o1.w = fmaxf(acc[i][7] + bv[7], 0.f) + xv1.w;
            *(float4*)&out[(size_t)row * DD + c0] = o0;
            *(float4*)&out[(size_t)row * DD + c0 + 4] = o1;
        }
    }
}

extern "C" void kernel_launch(void* const* d_in, const int* in_sizes, int n_in,
                              void* d_out, int out_size, void* d_ws, size_t ws_size,
                              hipStream_t stream) {
    const float* x = (const float*)d_in[0];
    const float* W = (const float*)d_in[1];
    const float* b = (const float*)d_in[2];
    const int*   ei = (const int*)d_in[3];
    int N = in_sizes[0] / DD;
    int E = in_sizes[3] / 2;
    float* out = (float*)d_out;
    float* outTail = out + (size_t)N * DD;

    int NB = (N + 511) >> BSH;          // buckets of 512 nodes
    int nA = (E + EPB - 1) / EPB;       // A-pass blocks

    // new-path workspace layout
    char* wsb = (char*)d_ws;
    size_t off = 0;
    unsigned* brec = (unsigned*)(wsb + off);  off += (size_t)E * 4;
    unsigned* recs = (unsigned*)(wsb + off);  off += (size_t)E * 4;
    unsigned* xs   = (unsigned*)(wsb + off);  off += (size_t)N * 64 * 4;
    unsigned* aggh = (unsigned*)(wsb + off);  off += (size_t)N * 64 * 4;
    ushort*   Wt   = (ushort*)(wsb + off);    off += (size_t)DD * DD * 2;
    int* H         = (int*)(wsb + off);       off += (size_t)nA * NB * 4;
    int* bucketstart = (int*)(wsb + off);     off += (size_t)(NB + 1) * 4;
    int* colsum    = (int*)(wsb + off);       off += (size_t)NB * 4;
    int* rowstart  = (int*)(wsb + off);       off += (size_t)(N + 1) * 4;
    float* invs    = (float*)(wsb + off);     off += (size_t)N * 4;
    int* flag      = (int*)(wsb + off);       off += 64;

    bool newpath = (ws_size >= off) && (NB <= 256) && (nA <= 1024) && (N <= 131072);

    if (newpath) {
        k_sniff<<<1, 1024, 0, stream>>>(ei, 1024, flag);
        kA1<<<nA, 256, 0, stream>>>(ei, E, NB, outTail, H, flag);
        k_scanH1<<<NB, 256, 0, stream>>>(H, nA, NB, colsum);
        k_scanH2<<<1, 256, 0, stream>>>(colsum, NB, E, bucketstart);
        kA2<<<nA, 256, 0, stream>>>(ei, E, NB, H, bucketstart, brec, flag);
        kB<<<NB, 256, 0, stream>>>(brec, bucketstart, NB, N, E, recs, rowstart, invs);
        int n2 = N * 64;
        k_cvt_xs<<<(n2 + 255) / 256, 256, 0, stream>>>((const float2*)x, invs, xs, n2);
        k_cvt_W<<<(DD * DD + 255) / 256, 256, 0, stream>>>(W, Wt);
        k_agg_s<<<(N + 3) / 4, 256, 0, stream>>>(xs, rowstart, invs, recs, N, aggh);
        k_gemm_mfma<<<(N + 63) / 64, 256, 0, stream>>>((const ushort*)aggh, Wt, b, x, out, N);
    } else {
        // fallback: round-4 rank-based build + f32 compute (known good)
        off = 0;
        unsigned* recsF = (unsigned*)(wsb + off);  off += (size_t)E * 4;
        unsigned* rank  = (unsigned*)(wsb + off);  off += (size_t)E * 4;
        int* cnt        = (int*)(wsb + off);       off += (size_t)N * 4;
        int* rowstartF  = (int*)(wsb + off);       off += (size_t)(N + 1) * 4;
        float* invsF    = (float*)(wsb + off);     off += (size_t)N * 4;
        int* bsum       = (int*)(wsb + off);       off += 512 * 4;
        int* boff       = (int*)(wsb + off);       off += 512 * 4;
        int* flagF      = (int*)(wsb + off);

        hipMemsetAsync(cnt, 0, sizeof(int) * (size_t)N, stream);
        k_sniff<<<1, 1024, 0, stream>>>(ei, 1024, flagF);
        k_count_echo<<<(E + 255) / 256, 256, 0, stream>>>(ei, E, cnt, outTail, rank, flagF);
        int nblk = (N + 1023) / 1024;
        k_scan1<<<nblk, 1024, 0, stream>>>(cnt, N, rowstartF, bsum);
        k_scan2<<<1, 128, 0, stream>>>(bsum, nblk, boff);
        k_scan3<<<(N + 255) / 256, 256, 0, stream>>>(N, E, rowstartF, boff, cnt, invsF);
        k_fill_r<<<(E + 255) / 256, 256, 0, stream>>>(ei, E, rowstartF, rank, recsF, flagF);
        k_agg_f32<<<(N + 3) / 4, 256, 0, stream>>>(x, rowstartF, invsF, recsF, N, out);
        k_gemm_f32<<<(N + GROWS - 1) / GROWS, 128, 0, stream>>>(out, W, b, x, N);
    }
}